// Round 10
// baseline (1253.467 us; speedup 1.0000x reference)
//
#include <hip/hip_runtime.h>
#include <cstdint>

typedef unsigned short u16;
typedef __attribute__((ext_vector_type(8))) __bf16 bf16x8;
typedef __attribute__((ext_vector_type(4))) float f32x4;

#define TOK 4096
#define DM  1024
#define EXP 8
#define FF  4096
#define SEQ 512
#define NH  8
#define HD  128
#define JOBCAP 10496

__device__ __forceinline__ u16 f2bf(float f) {
  union { float f; unsigned int u; } v; v.f = f;
  unsigned int u = v.u;
  u += 0x7FFFu + ((u >> 16) & 1u);   // round-to-nearest-even
  return (u16)(u >> 16);
}
__device__ __forceinline__ float bf2f(u16 h) {
  union { unsigned int u; float f; } v; v.u = ((unsigned int)h) << 16; return v.f;
}

// async global->LDS, 16B per lane; dest = wave-uniform base + lane*16
__device__ __forceinline__ void gl_lds16(const u16* g, u16* l) {
  __builtin_amdgcn_global_load_lds(
      (const __attribute__((address_space(1))) unsigned int*)g,
      (__attribute__((address_space(3))) unsigned int*)l, 16, 0, 0);
}

// ---------------- embed gather ----------------
__global__ void k_embed(const int* __restrict__ ids, const float* __restrict__ emb,
                        float* __restrict__ x) {
  int t = blockIdx.x;
  int id = ids[t];
  const float4* src = (const float4*)(emb + (size_t)id * DM);
  float4* dst = (float4*)(x + (size_t)t * DM);
  dst[threadIdx.x] = src[threadIdx.x];
}

// ---------------- layernorm -> bf16 (MoE path) ----------------
__global__ void k_ln(const float* __restrict__ in, const float* __restrict__ g,
                     const float* __restrict__ be, u16* __restrict__ obf) {
  int t = blockIdx.x, tid = threadIdx.x;
  float4 v = ((const float4*)(in + (size_t)t * DM))[tid];
  float s = v.x + v.y + v.z + v.w;
  float sq = v.x*v.x + v.y*v.y + v.z*v.z + v.w*v.w;
  for (int o = 32; o; o >>= 1) { s += __shfl_down(s, o); sq += __shfl_down(sq, o); }
  __shared__ float ss[4], sqs[4];
  if ((tid & 63) == 0) { ss[tid >> 6] = s; sqs[tid >> 6] = sq; }
  __syncthreads();
  s  = ss[0] + ss[1] + ss[2] + ss[3];
  sq = sqs[0] + sqs[1] + sqs[2] + sqs[3];
  float mean = s * (1.f / DM);
  float var  = sq * (1.f / DM) - mean * mean;
  float rstd = rsqrtf(var + 1e-5f);
  float4 gg = ((const float4*)g)[tid];
  float4 bb = ((const float4*)be)[tid];
  ushort4 u;
  u.x = f2bf((v.x - mean) * rstd * gg.x + bb.x);
  u.y = f2bf((v.y - mean) * rstd * gg.y + bb.y);
  u.z = f2bf((v.z - mean) * rstd * gg.z + bb.z);
  u.w = f2bf((v.w - mean) * rstd * gg.w + bb.w);
  ((ushort4*)(obf + (size_t)t * DM))[tid] = u;
}

// ---------------- layernorm -> hi/lo bf16 pair (attention path) ----------------
__global__ void k_ln2(const float* __restrict__ in, const float* __restrict__ g,
                      const float* __restrict__ be, u16* __restrict__ oh,
                      u16* __restrict__ ol) {
  int t = blockIdx.x, tid = threadIdx.x;
  float4 v = ((const float4*)(in + (size_t)t * DM))[tid];
  float s = v.x + v.y + v.z + v.w;
  float sq = v.x*v.x + v.y*v.y + v.z*v.z + v.w*v.w;
  for (int o = 32; o; o >>= 1) { s += __shfl_down(s, o); sq += __shfl_down(sq, o); }
  __shared__ float ss[4], sqs[4];
  if ((tid & 63) == 0) { ss[tid >> 6] = s; sqs[tid >> 6] = sq; }
  __syncthreads();
  s  = ss[0] + ss[1] + ss[2] + ss[3];
  sq = sqs[0] + sqs[1] + sqs[2] + sqs[3];
  float mean = s * (1.f / DM);
  float var  = sq * (1.f / DM) - mean * mean;
  float rstd = rsqrtf(var + 1e-5f);
  float4 gg = ((const float4*)g)[tid];
  float4 bb = ((const float4*)be)[tid];
  float o4[4];
  o4[0] = (v.x - mean) * rstd * gg.x + bb.x;
  o4[1] = (v.y - mean) * rstd * gg.y + bb.y;
  o4[2] = (v.z - mean) * rstd * gg.z + bb.z;
  o4[3] = (v.w - mean) * rstd * gg.w + bb.w;
  ushort4 uh, ul;
  u16* ph = (u16*)&uh; u16* pl = (u16*)&ul;
  #pragma unroll
  for (int i = 0; i < 4; i++) {
    u16 hi = f2bf(o4[i]); ph[i] = hi; pl[i] = f2bf(o4[i] - bf2f(hi));
  }
  ((ushort4*)(oh + (size_t)t * DM))[tid] = uh;
  ((ushort4*)(ol + (size_t)t * DM))[tid] = ul;
}

// ---------------- transpose f32 [K,N] -> hi/lo bf16 [N,K] ----------------
__global__ void k_tcvt_split(const float* __restrict__ src, u16* __restrict__ dh,
                             u16* __restrict__ dl, int K, int N) {
  __shared__ float t[32][33];
  int k0 = blockIdx.x * 32, n0 = blockIdx.y * 32;
  int tx = threadIdx.x, ty = threadIdx.y;
  #pragma unroll
  for (int i = 0; i < 4; i++) t[ty + 8*i][tx] = src[(size_t)(k0 + ty + 8*i) * N + n0 + tx];
  __syncthreads();
  int u = ty * 32 + tx;
  int r = u >> 3, kq = u & 7;
  ushort4 oh, ol;
  u16* ph = (u16*)&oh; u16* pl = (u16*)&ol;
  #pragma unroll
  for (int i = 0; i < 4; i++) {
    float v = t[kq*4+i][r];
    u16 hi = f2bf(v); ph[i] = hi; pl[i] = f2bf(v - bf2f(hi));
  }
  *(ushort4*)&dh[(size_t)(n0 + r) * K + k0 + kq*4] = oh;
  *(ushort4*)&dl[(size_t)(n0 + r) * K + k0 + kq*4] = ol;
}

// ---------------- transpose f32 [K,N] -> bf16 [N,K], z-batched (MoE weights) ----------------
__global__ void k_tcvt(const float* __restrict__ src, u16* __restrict__ dst, int K, int N) {
  __shared__ float t[32][33];
  size_t zoff = (size_t)blockIdx.z * K * N;
  src += zoff;
  u16* d = dst + zoff;
  int k0 = blockIdx.x * 32, n0 = blockIdx.y * 32;
  int tx = threadIdx.x, ty = threadIdx.y;
  #pragma unroll
  for (int i = 0; i < 4; i++) t[ty + 8*i][tx] = src[(size_t)(k0 + ty + 8*i) * N + n0 + tx];
  __syncthreads();
  int u = ty * 32 + tx;
  int r = u >> 3, kq = u & 7;
  ushort4 o;
  o.x = f2bf(t[kq*4+0][r]); o.y = f2bf(t[kq*4+1][r]);
  o.z = f2bf(t[kq*4+2][r]); o.w = f2bf(t[kq*4+3][r]);
  *(ushort4*)&d[(size_t)(n0 + r) * K + k0 + kq*4] = o;
}

// ---------------- causal softmax f32 -> att hi/lo bf16 in place ----------------
__global__ void k_softmax_h(float* __restrict__ scores) {
  int q = blockIdx.x, bh = blockIdx.y, tid = threadIdx.x;
  float* row = scores + ((size_t)bh * 512 + q) * 512;
  u16* orow = (u16*)row;
  const float scale = 0.088388347648318447f; // 128^-0.5
  int j0 = tid * 2;
  float v0 = -1e30f, v1 = -1e30f;
  if (j0 <= q)     v0 = row[j0] * scale;
  if (j0 + 1 <= q) v1 = row[j0 + 1] * scale;
  float m = fmaxf(v0, v1);
  for (int o = 32; o; o >>= 1) m = fmaxf(m, __shfl_down(m, o));
  __shared__ float sm[4], ssum[4];
  if ((tid & 63) == 0) sm[tid >> 6] = m;
  __syncthreads();
  m = fmaxf(fmaxf(sm[0], sm[1]), fmaxf(sm[2], sm[3]));
  float p0 = (j0 <= q)     ? expf(v0 - m) : 0.f;
  float p1 = (j0 + 1 <= q) ? expf(v1 - m) : 0.f;
  float s = p0 + p1;
  for (int o = 32; o; o >>= 1) s += __shfl_down(s, o);
  if ((tid & 63) == 0) ssum[tid >> 6] = s;
  __syncthreads();
  s = ssum[0] + ssum[1] + ssum[2] + ssum[3];
  float inv = 1.f / s;
  float pi0 = p0 * inv, pi1 = p1 * inv;
  u16 h0 = f2bf(pi0), h1 = f2bf(pi1);
  orow[j0]       = h0; orow[j0 + 1]       = h1;
  orow[512 + j0] = f2bf(pi0 - bf2f(h0));
  orow[512 + j0 + 1] = f2bf(pi1 - bf2f(h1));
}

// ---------------- split-bf16 3-pass MFMA GEMM (attention path) ----------------
constexpr int HOP_QKV    = 0;
constexpr int HOP_SCORES = 1;
constexpr int HOP_PV     = 2;
constexpr int HOP_PROJ   = 3;

struct GemmHArgs {
  const u16 *Ah, *Al, *Bh, *Bl;
  u16 *D0h, *D0l, *D1h, *D1l, *D2h, *D2l;
  float *Cf;
  const float *bias, *resid, *pos;
  int lda, ldb, K;
};

template<int OP>
__launch_bounds__(256)
__global__ void gemm_h(GemmHArgs p) {
  int bx, by, z;
  if constexpr (OP == HOP_QKV) {
    int bid = blockIdx.x; int xcd = bid & 7, slot = bid >> 3;
    by = xcd * 3 + (slot >> 5); bx = slot & 31; z = 0;
  } else if constexpr (OP == HOP_PROJ) {
    int bid = blockIdx.x; by = bid & 7; bx = bid >> 3; z = 0;
  } else if constexpr (OP == HOP_SCORES) { // dense triangular: 10 tiles x 64 bh
    int bid = blockIdx.x; z = bid / 10; int t = bid % 10;
    bx = (t >= 6) ? 3 : (t >= 3) ? 2 : (t >= 1) ? 1 : 0;
    by = t - ((bx * (bx + 1)) >> 1);
  } else {
    bx = blockIdx.x; by = blockIdx.y; z = blockIdx.z;
  }

  const u16 *Ahb, *Alb, *Bhb, *Blb;
  if constexpr (OP == HOP_SCORES) {
    size_t off = (size_t)(z >> 3) * 524288 + (size_t)(z & 7) * 128;
    Ahb = p.Ah + off; Alb = p.Al + off; Bhb = p.Bh + off; Blb = p.Bl + off;
  } else if constexpr (OP == HOP_PV) {
    size_t aoff = (size_t)z * 524288;
    Ahb = p.Ah + aoff; Alb = p.Ah + aoff + 512;
    size_t boff = (size_t)z * 65536;
    Bhb = p.Bh + boff; Blb = p.Bl + boff;
  } else {
    Ahb = p.Ah; Alb = p.Al; Bhb = p.Bh; Blb = p.Bl;
  }

  int kmax = p.K;
  if constexpr (OP == HOP_PV) { int lim = bx * 128 + 128; kmax = lim < p.K ? lim : p.K; }
  int nt = kmax >> 5;

  __shared__ __align__(16) u16 As[2 * 4096];
  __shared__ __align__(16) u16 Bs[2 * 4096];

  int tid = threadIdx.x, lane = tid & 63, wid = tid >> 6;
  int srow = wid * 16 + (lane >> 2), skoff = (lane & 3) * 8;
  int lo0 = (wid * 16) * 32, lo1 = ((wid + 4) * 16) * 32;
  int wr = wid >> 1, wc = wid & 1, fm = lane & 15, fk = (lane >> 4) * 8;

  f32x4 acc[4][4] = {};
  const size_t lda = p.lda, ldb = p.ldb;

  #pragma unroll 1
  for (int pass = 0; pass < 3; ++pass) {
    const u16* Ab = (pass < 2) ? Ahb : Alb;
    const u16* Bb = (pass & 1) ? Blb : Bhb;
    const u16* aptr0 = Ab + (size_t)(bx * 128 + srow) * lda + skoff;
    const u16* aptr1 = Ab + (size_t)(bx * 128 + 64 + srow) * lda + skoff;
    const u16* bptr0 = Bb + (size_t)(by * 128 + srow) * ldb + skoff;
    const u16* bptr1 = Bb + (size_t)(by * 128 + 64 + srow) * ldb + skoff;

    gl_lds16(aptr0, &As[lo0]); gl_lds16(aptr1, &As[lo1]);
    gl_lds16(bptr0, &Bs[lo0]); gl_lds16(bptr1, &Bs[lo1]);
    __syncthreads();
    int cur = 0;
    for (int t = 0; t < nt; ++t) {
      if (t + 1 < nt) {
        int nxt = (cur ^ 1) * 4096;
        int k0 = (t + 1) * 32;
        gl_lds16(aptr0 + k0, &As[nxt + lo0]); gl_lds16(aptr1 + k0, &As[nxt + lo1]);
        gl_lds16(bptr0 + k0, &Bs[nxt + lo0]); gl_lds16(bptr1 + k0, &Bs[nxt + lo1]);
      }
      int cb = cur * 4096;
      bf16x8 af[4], bfr[4];
      #pragma unroll
      for (int i = 0; i < 4; ++i) {
        af[i]  = *(const bf16x8*)&As[cb + (wr * 64 + i * 16 + fm) * 32 + fk];
        bfr[i] = *(const bf16x8*)&Bs[cb + (wc * 64 + i * 16 + fm) * 32 + fk];
      }
      #pragma unroll
      for (int mi = 0; mi < 4; ++mi)
        #pragma unroll
        for (int ni = 0; ni < 4; ++ni)
          acc[mi][ni] = __builtin_amdgcn_mfma_f32_16x16x32_bf16(af[mi], bfr[ni], acc[mi][ni], 0, 0, 0);
      __syncthreads();
      cur ^= 1;
    }
  }

  int rb = (lane >> 4) * 4, cl = lane & 15;
  #pragma unroll
  for (int mi = 0; mi < 4; ++mi)
    #pragma unroll
    for (int ni = 0; ni < 4; ++ni)
      #pragma unroll
      for (int j = 0; j < 4; ++j) {
        int m = bx * 128 + wr * 64 + mi * 16 + rb + j;
        int n = by * 128 + wc * 64 + ni * 16 + cl;
        float v = acc[mi][ni][j];
        if constexpr (OP == HOP_QKV) {
          u16 hi = f2bf(v); u16 lo = f2bf(v - bf2f(hi));
          int sel = n >> 10, nn = n & 1023;
          if (sel == 0) {
            p.D0h[(size_t)m * DM + nn] = hi; p.D0l[(size_t)m * DM + nn] = lo;
          } else if (sel == 1) {
            p.D1h[(size_t)m * DM + nn] = hi; p.D1l[(size_t)m * DM + nn] = lo;
          } else {
            size_t idx = (size_t)((m >> 9) * 8 + (nn >> 7)) * 65536 + (size_t)(nn & 127) * 512 + (m & 511);
            p.D2h[idx] = hi; p.D2l[idx] = lo;
          }
        } else if constexpr (OP == HOP_SCORES) {
          p.Cf[(size_t)z * 262144 + (size_t)m * 512 + n] = v;
        } else if constexpr (OP == HOP_PV) {
          u16 hi = f2bf(v); u16 lo = f2bf(v - bf2f(hi));
          size_t idx = (size_t)(z >> 3) * 524288 + (size_t)m * 1024 + (size_t)(z & 7) * 128 + n;
          p.D0h[idx] = hi; p.D0l[idx] = lo;
        } else { // HOP_PROJ
          size_t idx = (size_t)m * 1024 + n;
          p.Cf[idx] = v + p.bias[n] + p.resid[idx] + p.pos[(size_t)(m & 511) * 1024 + n];
        }
      }
}

// ---------------- MOE1: bf16 MFMA 256x256 8-phase counted-vmcnt GEMM ----------------
// 8 waves (2M x 4N), BK=64, 2-K-tile LDS dbuf (128KB), per-wave 128x64 interleaved
// across halves: rows mh*128 + wr*64 + mi*16, cols nh*128 + wcc*32 + ni*16.
// Quadrant order (0,0),(0,1),(1,1),(1,0); one half-tile staged per phase into the
// region freed one barrier earlier; vmcnt(4) once per K-tile. XOR swizzle (16B gran)
// applied on pre-swizzled global source + swizzled ds_read (both-sides, rule 21).
struct GemmM1Args {
  const u16* A; const u16* B; u16* C;
  const float* bias;
  const int* joblist; const int* seg;
};

__launch_bounds__(512, 2)
__global__ void gemm_m1(GemmM1Args p) {
  int bid = blockIdx.x;
  int xcd = bid & 7, slot = bid >> 3;   // grid 656 = 8 x 82
  int by = xcd * 2 + (slot & 1);        // 0..15
  int bx = slot >> 1;                   // 0..40
  int r0g = bx * 256;
  if (r0g >= p.seg[8]) return;
  int z = 0;
  #pragma unroll
  for (int e = 1; e < 8; ++e) z += (r0g >= p.seg[e]) ? 1 : 0;
  const u16* Bb = p.B + (size_t)z * 4194304;

  extern __shared__ u16 sh[];           // 128KB: [d][A0|A1|B0|B1], 8192 u16 each

  int tid = threadIdx.x, lane = tid & 63, wid = tid >> 6;
  int wr = wid >> 2, wcc = wid & 3;

  // staging: lane covers rows wid*8 + j*64 + (lane>>3); source k pre-swizzled
  int srow = wid * 8 + (lane >> 3);
  int kk = ((lane & 7) * 8) ^ ((srow & 7) << 3);
  const u16 *aSrc[2][2], *bSrc[2][2];
  #pragma unroll
  for (int h = 0; h < 2; ++h) {
    int j0 = p.joblist[r0g + h * 128 + srow];
    int j1 = p.joblist[r0g + h * 128 + 64 + srow];
    aSrc[h][0] = p.A + (size_t)(j0 < 0 ? 0 : j0) * 1024 + kk;
    aSrc[h][1] = p.A + (size_t)(j1 < 0 ? 0 : j1) * 1024 + kk;
    bSrc[h][0] = Bb + (size_t)(by * 256 + h * 128 + srow) * 1024 + kk;
    bSrc[h][1] = Bb + (size_t)(by * 256 + h * 128 + 64 + srow) * 1024 + kk;
  }
  u16* shW = sh + wid * 512;            // wave-uniform dest base

#define STG_A(T, H) { u16* d_ = shW + ((T)&1)*32768 + (H)*8192;            \
    gl_lds16(aSrc[H][0] + (T)*64, d_); gl_lds16(aSrc[H][1] + (T)*64, d_ + 4096); }
#define STG_B(T, H) { u16* d_ = shW + ((T)&1)*32768 + 16384 + (H)*8192;    \
    gl_lds16(bSrc[H][0] + (T)*64, d_); gl_lds16(bSrc[H][1] + (T)*64, d_ + 4096); }
#define MM_CLOSE() { __builtin_amdgcn_sched_barrier(0);                    \
    __builtin_amdgcn_s_barrier(); __builtin_amdgcn_sched_barrier(0); }

  int fm = lane & 15;
  int swz = (fm & 7) << 3;
  int kkr0 = ((lane >> 4) * 8) ^ swz;
  int kkr1 = (32 + (lane >> 4) * 8) ^ swz;
  int rAbase = (wr * 64 + fm) * 64;
  int rBbase = (wcc * 32 + fm) * 64;

  f32x4 acc[2][2][4][2] = {};   // [mh][nh][mi][ni]

  // prologue: A0(0),B1(0),A1(0),B0(0),A0(1),B1(1) -> wait tile 0 (oldest 8 of 12)
  STG_A(0,0); STG_B(0,1); STG_A(0,1); STG_B(0,0); STG_A(1,0); STG_B(1,1);
  asm volatile("s_waitcnt vmcnt(4)" ::: "memory");
  MM_CLOSE();

#define MM_PHASE(MH, NH, STAGE_CODE) {                                     \
    int d32 = (t & 1) * 32768;                                             \
    bf16x8 a_[4][2], b_[2][2];                                             \
    _Pragma("unroll") for (int mi = 0; mi < 4; ++mi) {                     \
      a_[mi][0] = *(const bf16x8*)&sh[d32 + (MH)*8192 + rAbase + mi*1024 + kkr0]; \
      a_[mi][1] = *(const bf16x8*)&sh[d32 + (MH)*8192 + rAbase + mi*1024 + kkr1]; \
    }                                                                      \
    _Pragma("unroll") for (int ni = 0; ni < 2; ++ni) {                     \
      b_[ni][0] = *(const bf16x8*)&sh[d32 + 16384 + (NH)*8192 + rBbase + ni*1024 + kkr0]; \
      b_[ni][1] = *(const bf16x8*)&sh[d32 + 16384 + (NH)*8192 + rBbase + ni*1024 + kkr1]; \
    }                                                                      \
    STAGE_CODE;                                                            \
    __builtin_amdgcn_sched_barrier(0);                                     \
    __builtin_amdgcn_s_barrier();                                          \
    asm volatile("s_waitcnt lgkmcnt(0)" ::: "memory");                     \
    __builtin_amdgcn_sched_barrier(0);                                     \
    __builtin_amdgcn_s_setprio(1);                                         \
    _Pragma("unroll") for (int ks = 0; ks < 2; ++ks)                       \
      _Pragma("unroll") for (int mi = 0; mi < 4; ++mi)                     \
        _Pragma("unroll") for (int ni = 0; ni < 2; ++ni)                   \
          acc[MH][NH][mi][ni] = __builtin_amdgcn_mfma_f32_16x16x32_bf16(   \
              a_[mi][ks], b_[ni][ks], acc[MH][NH][mi][ni], 0, 0, 0);       \
    __builtin_amdgcn_s_setprio(0);                                         \
  }

  #pragma unroll 1
  for (int t = 0; t < 16; ++t) {
    int s1 = (t + 1 < 16), s2 = (t + 2 < 16);
    MM_PHASE(0, 0, { if (s1) STG_A(t + 1, 1); });
    MM_CLOSE();
    MM_PHASE(0, 1, { if (s1) STG_B(t + 1, 0); });
    MM_CLOSE();
    MM_PHASE(1, 1, { if (s2) STG_A(t + 2, 0); });
    MM_CLOSE();
    MM_PHASE(1, 0, { if (s2) STG_B(t + 2, 1); });
    if (s1) {
      if (s2) { asm volatile("s_waitcnt vmcnt(4)" ::: "memory"); }
      else    { asm volatile("s_waitcnt vmcnt(0)" ::: "memory"); }
    }
    MM_CLOSE();
  }
#undef MM_PHASE
#undef STG_A
#undef STG_B
#undef MM_CLOSE

  int rb = (lane >> 4) * 4, cl = lane & 15;
  #pragma unroll
  for (int mh = 0; mh < 2; ++mh)
    #pragma unroll
    for (int nh = 0; nh < 2; ++nh)
      #pragma unroll
      for (int mi = 0; mi < 4; ++mi)
        #pragma unroll
        for (int ni = 0; ni < 2; ++ni)
          #pragma unroll
          for (int j = 0; j < 4; ++j) {
            int m = r0g + mh * 128 + wr * 64 + mi * 16 + rb + j;
            int n = by * 256 + nh * 128 + wcc * 32 + ni * 16 + cl;
            float v = acc[mh][nh][mi][ni][j] + p.bias[(size_t)z * FF + n];
            v = v > 0.f ? v : 0.f;
            p.C[(size_t)m * FF + n] = f2bf(v);
          }
}

// ---------------- MOE2: bf16 MFMA 128x128 TN GEMM, 2-phase dbuf ----------------
struct GemmArgs {
  const u16* A; const u16* B; void* C;
  const float* bias;
  const int* seg;
  int lda, ldb, K;
};

__launch_bounds__(256)
__global__ void gemm_k2(GemmArgs p) {
  int bid = blockIdx.x;                   // grid 656 = 8 x 82
  int xcd = bid & 7, slot = bid >> 3;
  int g = xcd * 82 + slot;
  int bx = g >> 3, by = g & 7;
  int r0g = bx * 128;
  if (r0g >= p.seg[8]) return;
  int z = 0;
  #pragma unroll
  for (int e = 1; e < 8; ++e) z += (r0g >= p.seg[e]) ? 1 : 0;
  const u16* Bbase = p.B + (size_t)z * 4194304;

  __shared__ __align__(16) u16 As[2 * 4096];
  __shared__ __align__(16) u16 Bs[2 * 4096];

  int tid = threadIdx.x;
  int lane = tid & 63, wid = tid >> 6;

  int srow = wid * 16 + (lane >> 2);
  int skoff = (lane & 3) * 8;

  const u16* aptr0 = p.A + (size_t)(r0g + srow) * p.lda + skoff;
  const u16* aptr1 = p.A + (size_t)(r0g + 64 + srow) * p.lda + skoff;
  const u16* bptr0 = Bbase + (size_t)(by * 128 + srow) * p.ldb + skoff;
  const u16* bptr1 = Bbase + (size_t)(by * 128 + 64 + srow) * p.ldb + skoff;

  int lo0 = (wid * 16) * 32;
  int lo1 = ((wid + 4) * 16) * 32;

  int wr = wid >> 1, wc = wid & 1;
  int fm = lane & 15;
  int fk = (lane >> 4) * 8;

  f32x4 acc[4][4] = {};
  int nt = p.K >> 5;

  gl_lds16(aptr0, &As[lo0]); gl_lds16(aptr1, &As[lo1]);
  gl_lds16(bptr0, &Bs[lo0]); gl_lds16(bptr1, &Bs[lo1]);
  __syncthreads();

  int cur = 0;
  for (int t = 0; t < nt; ++t) {
    if (t + 1 < nt) {
      int nxt = (cur ^ 1) * 4096;
      int k0 = (t + 1) * 32;
      gl_lds16(aptr0 + k0, &As[nxt + lo0]); gl_lds16(aptr1 + k0, &As[nxt + lo1]);
      gl_lds16(bptr0 + k0, &Bs[nxt + lo0]); gl_lds16(bptr1 + k0, &Bs[nxt + lo1]);
    }
    int cb = cur * 4096;
    bf16x8 af[4], bfr[4];
    #pragma unroll
    for (int i = 0; i < 4; ++i) {
      af[i]  = *(const bf16x8*)&As[cb + (wr * 64 + i * 16 + fm) * 32 + fk];
      bfr[i] = *(const bf16x8*)&Bs[cb + (wc * 64 + i * 16 + fm) * 32 + fk];
    }
    #pragma unroll
    for (int mi = 0; mi < 4; ++mi)
      #pragma unroll
      for (int ni = 0; ni < 4; ++ni)
        acc[mi][ni] = __builtin_amdgcn_mfma_f32_16x16x32_bf16(af[mi], bfr[ni], acc[mi][ni], 0, 0, 0);
    __syncthreads();
    cur ^= 1;
  }

  int rb = (lane >> 4) * 4;
  int cl = lane & 15;
  #pragma unroll
  for (int mi = 0; mi < 4; ++mi)
    #pragma unroll
    for (int ni = 0; ni < 4; ++ni)
      #pragma unroll
      for (int j = 0; j < 4; ++j) {
        int m = r0g + wr * 64 + mi * 16 + rb + j;
        int n = by * 128 + wc * 64 + ni * 16 + cl;
        ((float*)p.C)[(size_t)m * DM + n] = acc[mi][ni][j] + p.bias[(size_t)z * DM + n];
      }
}

// ---------------- router: inline fp32 LN + logits + noisy top-2 + gates ----------------
__global__ void k_router(const float* __restrict__ xin, const float* __restrict__ g,
                         const float* __restrict__ be,
                         const float* __restrict__ Wr, const float* __restrict__ br,
                         const float* __restrict__ Wn, const float* __restrict__ bn,
                         const float* __restrict__ noise,
                         float* __restrict__ gates, int* __restrict__ topidx) {
  int t = blockIdx.x, tid = threadIdx.x;
  float4 v = ((const float4*)(xin + (size_t)t * DM))[tid];
  float s = v.x + v.y + v.z + v.w;
  float sq = v.x*v.x + v.y*v.y + v.z*v.z + v.w*v.w;
  for (int o = 32; o; o >>= 1) { s += __shfl_down(s, o); sq += __shfl_down(sq, o); }
  __shared__ float ss[4], sqs[4];
  if ((tid & 63) == 0) { ss[tid >> 6] = s; sqs[tid >> 6] = sq; }
  __syncthreads();
  s  = ss[0] + ss[1] + ss[2] + ss[3];
  sq = sqs[0] + sqs[1] + sqs[2] + sqs[3];
  float mean = s * (1.f / DM);
  float var  = sq * (1.f / DM) - mean * mean;
  float rstd = rsqrtf(var + 1e-5f);
  float4 gg = ((const float4*)g)[tid];
  float4 bb = ((const float4*)be)[tid];
  float xl[4];
  xl[0] = (v.x - mean) * rstd * gg.x + bb.x;
  xl[1] = (v.y - mean) * rstd * gg.y + bb.y;
  xl[2] = (v.z - mean) * rstd * gg.z + bb.z;
  xl[3] = (v.w - mean) * rstd * gg.w + bb.w;
  float pl[8], pn[8];
  #pragma unroll
  for (int e = 0; e < 8; e++) { pl[e] = 0.f; pn[e] = 0.f; }
  #pragma unroll
  for (int j = 0; j < 4; j++) {
    int d = tid * 4 + j;
    float xv = xl[j];
    const float4* wr = (const float4*)(Wr + (size_t)d * 8);
    const float4* wn = (const float4*)(Wn + (size_t)d * 8);
    float4 a0 = wr[0], a1 = wr[1], c0 = wn[0], c1 = wn[1];
    pl[0] += xv * a0.x; pl[1] += xv * a0.y; pl[2] += xv * a0.z; pl[3] += xv * a0.w;
    pl[4] += xv * a1.x; pl[5] += xv * a1.y; pl[6] += xv * a1.z; pl[7] += xv * a1.w;
    pn[0] += xv * c0.x; pn[1] += xv * c0.y; pn[2] += xv * c0.z; pn[3] += xv * c0.w;
    pn[4] += xv * c1.x; pn[5] += xv * c1.y; pn[6] += xv * c1.z; pn[7] += xv * c1.w;
  }
  for (int o = 32; o; o >>= 1) {
    #pragma unroll
    for (int e = 0; e < 8; e++) { pl[e] += __shfl_down(pl[e], o); pn[e] += __shfl_down(pn[e], o); }
  }
  __shared__ float sl[4][8], sn[4][8];
  if ((tid & 63) == 0) {
    int w = tid >> 6;
    #pragma unroll
    for (int e = 0; e < 8; e++) { sl[w][e] = pl[e]; sn[w][e] = pn[e]; }
  }
  __syncthreads();
  if (tid == 0) {
    float noisy[8];
    #pragma unroll
    for (int e = 0; e < 8; e++) {
      float l  = sl[0][e] + sl[1][e] + sl[2][e] + sl[3][e] + br[e];
      float nn = sn[0][e] + sn[1][e] + sn[2][e] + sn[3][e] + bn[e];
      float sp = (nn > 20.f) ? nn : log1pf(expf(nn));
      noisy[e] = l + noise[(size_t)t * 8 + e] * sp;
    }
    int i0 = 0;
    for (int e = 1; e < 8; e++) if (noisy[e] > noisy[i0]) i0 = e;
    int i1 = (i0 == 0) ? 1 : 0;
    for (int e = 0; e < 8; e++) if (e != i0 && noisy[e] > noisy[i1]) i1 = e;
    float e1 = expf(noisy[i1] - noisy[i0]);
    float zz = 1.f + e1;
    gates[t * 2] = 1.f / zz; gates[t * 2 + 1] = e1 / zz;
    topidx[t * 2] = i0; topidx[t * 2 + 1] = i1;
  }
}

// ---------------- MoE bookkeeping ----------------
__global__ void k_moe_init(int* cnt, int* cnt2, int* joblist) {
  int i = blockIdx.x * 256 + threadIdx.x;
  if (i < JOBCAP) joblist[i] = -1;
  if (i < 8) { cnt[i] = 0; cnt2[i] = 0; }
}
__global__ void k_moe_count(const int* __restrict__ topidx, int* __restrict__ cnt) {
  int t = blockIdx.x * 256 + threadIdx.x;
  if (t >= TOK) return;
  atomicAdd(&cnt[topidx[t * 2]], 1);
  atomicAdd(&cnt[topidx[t * 2 + 1]], 1);
}
__global__ void k_moe_offsets(const int* __restrict__ cnt, int* __restrict__ seg) {
  if (threadIdx.x == 0) {
    int o = 0;
    for (int e = 0; e < 8; e++) { seg[e] = o; o += (cnt[e] + 255) & ~255; }  // pad to BM=256
    seg[8] = o;
  }
}
__global__ void k_moe_scatter(const int* __restrict__ topidx, int* __restrict__ cnt2,
                              const int* __restrict__ seg, int* __restrict__ joblist,
                              int* __restrict__ tokpos) {
  int t = blockIdx.x * 256 + threadIdx.x;
  if (t >= TOK) return;
  #pragma unroll
  for (int s = 0; s < 2; s++) {
    int e = topidx[t * 2 + s];
    int p = atomicAdd(&cnt2[e], 1);
    int pos = seg[e] + p;
    joblist[pos] = t;
    tokpos[t * 2 + s] = pos;
  }
}
__global__ void k_combine(const float* __restrict__ y, const float* __restrict__ gates,
                          const int* __restrict__ tokpos, float* __restrict__ out) {
  int t = blockIdx.x, tid = threadIdx.x;
  int p0 = tokpos[t * 2], p1 = tokpos[t * 2 + 1];
  float g0 = gates[t * 2], g1 = gates[t * 2 + 1];
  float4 a = ((const float4*)(y + (size_t)p0 * DM))[tid];
  float4 b = ((const float4*)(y + (size_t)p1 * DM))[tid];
  float4 o;
  o.x = g0 * a.x + g1 * b.x; o.y = g0 * a.y + g1 * b.y;
  o.z = g0 * a.z + g1 * b.z; o.w = g0 * a.w + g1 * b.w;
  ((float4*)(out + (size_t)t * DM))[tid] = o;
}

// ---------------- feature mean (two-stage) + classifier ----------------
__global__ void k_feat1(const float* __restrict__ second, float* __restrict__ part) {
  int b = blockIdx.x, c = blockIdx.y, tid = threadIdx.x;
  const float* p = second + ((size_t)b * SEQ + (size_t)c * 64) * DM;
  float4 s = {0.f, 0.f, 0.f, 0.f};
  for (int j = 0; j < 64; ++j) {
    float4 v = ((const float4*)(p + (size_t)j * DM))[tid];
    s.x += v.x; s.y += v.y; s.z += v.z; s.w += v.w;
  }
  ((float4*)(part + (size_t)(b * 8 + c) * DM))[tid] = s;
}
__global__ void k_feat2(const float* __restrict__ part, float* __restrict__ feat) {
  int i = blockIdx.x * 256 + threadIdx.x;
  int b = i >> 10, d = i & 1023;
  float s = 0.f;
  #pragma unroll
  for (int c = 0; c < 8; ++c) s += part[(size_t)(b * 8 + c) * DM + d];
  feat[i] = s * (1.f / SEQ);
}
__global__ void k_cls(const float* __restrict__ feat, const float* __restrict__ Wc,
                      const float* __restrict__ bc, float* __restrict__ cls) {
  int o = blockIdx.x; int b = o / 10, n = o % 10; int l = threadIdx.x;
  float s = 0.f;
  for (int d = l; d < DM; d += 64) s += feat[b * DM + d] * Wc[(size_t)d * 10 + n];
  for (int off = 32; off; off >>= 1) s += __shfl_down(s, off);
  if (l == 0) cls[o] = s + bc[n];
}

// ---------------- launch ----------------
extern "C" void kernel_launch(void* const* d_in, const int* in_sizes, int n_in,
                              void* d_out, int out_size, void* d_ws, size_t ws_size,
                              hipStream_t stream) {
  const int*   ids    = (const int*)d_in[0];
  const float* emb    = (const float*)d_in[2];
  const float* pos    = (const float*)d_in[3];
  const float* Wq     = (const float*)d_in[4];
  const float* Wk     = (const float*)d_in[5];
  const float* Wv     = (const float*)d_in[6];
  const float* Wo     = (const float*)d_in[7];
  const float* bo     = (const float*)d_in[8];
  const float* g1     = (const float*)d_in[9];
  const float* be1    = (const float*)d_in[10];
  const float* g2     = (const float*)d_in[11];
  const float* be2    = (const float*)d_in[12];
  const float* g3     = (const float*)d_in[13];
  const float* be3    = (const float*)d_in[14];
  const float* Wr1    = (const float*)d_in[15];
  const float* br1    = (const float*)d_in[16];
  const float* Wn1    = (const float*)d_in[17];
  const float* bn1    = (const float*)d_in[18];
  const float* W1a    = (const float*)d_in[19];
  const float* b1a    = (const float*)d_in[20];
  const float* W2a    = (const float*)d_in[21];
  const float* b2a    = (const float*)d_in[22];
  const float* Wr2    = (const float*)d_in[23];
  const float* br2    = (const float*)d_in[24];
  const float* Wn2    = (const float*)d_in[25];
  const float* bn2    = (const float*)d_in[26];
  const float* W1b    = (const float*)d_in[27];
  const float* b1b    = (const float*)d_in[28];
  const float* W2b    = (const float*)d_in[29];
  const float* b2b    = (const float*)d_in[30];
  const float* noise1 = (const float*)d_in[31];
  const float* noise2 = (const float*)d_in[32];
  const float* Wc     = (const float*)d_in[33];
  const float* bc     = (const float*)d_in[34];

  char* wsp = (char*)d_ws; size_t off = 0;
  auto alloc = [&](size_t bytes) -> void* {
    void* p = wsp + off; off += (bytes + 255) & ~(size_t)255; return p;
  };
  char*  G     = (char*)alloc(196083712);              // phase-overlaid big region
  float* x     = (float*)alloc((size_t)TOK * DM * 4);
  float* x2    = (float*)alloc((size_t)TOK * DM * 4);
  u16*   xlnb  = (u16*)alloc((size_t)TOK * DM * 2);
  float* gates  = (float*)alloc(TOK * 2 * 4);
  int*   topidx = (int*)alloc(TOK * 2 * 4);
  int*   cnt    = (int*)alloc(8 * 4);
  int*   cnt2   = (int*)alloc(8 * 4);
  int*   seg    = (int*)alloc(16 * 4);
  int*   joblist= (int*)alloc(JOBCAP * 4);
  int*   tokpos = (int*)alloc(TOK * 2 * 4);
  float* fpart  = (float*)alloc(64 * DM * 4);
  (void)ws_size; (void)in_sizes; (void)n_in; (void)out_size;

  // attention-phase views (~164MB of G)
  u16* WQKVTh = (u16*)(G + 0);            // [3072][1024]
  u16* WQKVTl = (u16*)(G + 6291456);
  u16* WOTh   = (u16*)(G + 12582912);
  u16* WOTl   = (u16*)(G + 14680064);
  u16* XLNH   = (u16*)(G + 16777216);
  u16* XLNL   = (u16*)(G + 25165824);
  u16* QH     = (u16*)(G + 33554432);
  u16* QL     = (u16*)(G + 41943040);
  u16* KH     = (u16*)(G + 50331648);
  u16* KL     = (u16*)(G + 58720256);
  u16* VTh    = (u16*)(G + 67108864);     // [64][128][512]
  u16* VTl    = (u16*)(G + 75497472);
  u16* OH     = (u16*)(G + 83886080);
  u16* OL     = (u16*)(G + 92274688);
  float* SC   = (float*)(G + 100663296);  // [64][512][512] f32 -> att hi/lo in place
  // moe-phase views (196MB of G; attention buffers dead by then)
  u16*   H    = (u16*)(G + 0);            // [10496][4096] bf16 (86MB)
  float* Y    = (float*)(G + 85983232);   // [10496][1024] f32 (43MB)
  u16*   WBUF = (u16*)(G + 128974848);    // expert weights bf16 (64MB), reused W1->W2

  float* out_first  = (float*)d_out;
  float* out_second = out_first + (size_t)TOK * DM;
  float* feat       = out_first + (size_t)2 * TOK * DM;
  float* cls        = feat + 8 * DM;

  dim3 tb(32, 8);
  // ---- attention phase: split-bf16 3-pass ----
  hipLaunchKernelGGL(k_tcvt_split, dim3(32, 32), tb, 0, stream, Wq, WQKVTh,            WQKVTl,            DM, DM);
  hipLaunchKernelGGL(k_tcvt_split, dim3(32, 32), tb, 0, stream, Wk, WQKVTh + 1048576,  WQKVTl + 1048576,  DM, DM);
  hipLaunchKernelGGL(k_tcvt_split, dim3(32, 32), tb, 0, stream, Wv, WQKVTh + 2097152,  WQKVTl + 2097152,  DM, DM);
  hipLaunchKernelGGL(k_tcvt_split, dim3(32, 32), tb, 0, stream, Wo, WOTh,              WOTl,              DM, DM);
  hipLaunchKernelGGL(k_embed, dim3(TOK), dim3(256), 0, stream, ids, emb, x);
  hipLaunchKernelGGL(k_ln2, dim3(TOK), dim3(256), 0, stream, x, g1, be1, XLNH, XLNL);

  GemmHArgs qa{};
  qa.Ah = XLNH; qa.Al = XLNL; qa.Bh = WQKVTh; qa.Bl = WQKVTl;
  qa.D0h = QH; qa.D0l = QL; qa.D1h = KH; qa.D1l = KL; qa.D2h = VTh; qa.D2l = VTl;
  qa.lda = DM; qa.ldb = DM; qa.K = DM;
  hipLaunchKernelGGL(gemm_h<HOP_QKV>, dim3(768), dim3(256), 0, stream, qa);

  GemmHArgs sa{};
  sa.Ah = QH; sa.Al = QL; sa.Bh = KH; sa.Bl = KL; sa.Cf = SC;
  sa.lda = DM; sa.ldb = DM; sa.K = HD;
  hipLaunchKernelGGL(gemm_h<HOP_SCORES>, dim3(640), dim3(256), 0, stream, sa);
  hipLaunchKernelGGL(k_softmax_h, dim3(SEQ, 64), dim3(256), 0, stream, SC);

  GemmHArgs pa{};
  pa.Ah = (const u16*)SC; pa.Bh = VTh; pa.Bl = VTl;
  pa.D0h = OH; pa.D0l = OL;
  pa.lda = 1024; pa.ldb = 512; pa.K = SEQ;
  hipLaunchKernelGGL(gemm_h<HOP_PV>, dim3(4, 1, 64), dim3(256), 0, stream, pa);

  GemmHArgs pj{};
  pj.Ah = OH; pj.Al = OL; pj.Bh = WOTh; pj.Bl = WOTl; pj.Cf = x2;
  pj.bias = bo; pj.resid = x; pj.pos = pos;
  pj.lda = DM; pj.ldb = DM; pj.K = DM;
  hipLaunchKernelGGL(gemm_h<HOP_PROJ>, dim3(256), dim3(256), 0, stream, pj);

  // ---- MoE phase ----
  auto run_moe = [&](const float* g, const float* be, const float* Wr, const float* br,
                     const float* Wn, const float* bn, const float* noise,
                     const float* W1, const float* b1, const float* W2, const float* b2,
                     float* outp) {
    hipLaunchKernelGGL(k_ln, dim3(TOK), dim3(256), 0, stream, x2, g, be, xlnb);
    hipLaunchKernelGGL(k_router, dim3(TOK), dim3(256), 0, stream, x2, g, be, Wr, br, Wn, bn, noise, gates, topidx);
    hipLaunchKernelGGL(k_moe_init, dim3(41), dim3(256), 0, stream, cnt, cnt2, joblist);
    hipLaunchKernelGGL(k_moe_count, dim3(16), dim3(256), 0, stream, topidx, cnt);
    hipLaunchKernelGGL(k_moe_offsets, dim3(1), dim3(64), 0, stream, cnt, seg);
    hipLaunchKernelGGL(k_moe_scatter, dim3(16), dim3(256), 0, stream, topidx, cnt2, seg, joblist, tokpos);
    hipLaunchKernelGGL(k_tcvt, dim3(32, 128, 8), tb, 0, stream, W1, WBUF, DM, FF);
    GemmM1Args m1{};
    m1.A = xlnb; m1.B = WBUF; m1.C = H; m1.bias = b1; m1.joblist = joblist; m1.seg = seg;
    hipLaunchKernelGGL(gemm_m1, dim3(656), dim3(512), 131072, stream, m1);
    hipLaunchKernelGGL(k_tcvt, dim3(128, 32, 8), tb, 0, stream, W2, WBUF, FF, DM);
    GemmArgs m2{};
    m2.A = H; m2.B = WBUF; m2.C = Y; m2.bias = b2; m2.seg = seg;
    m2.lda = FF; m2.ldb = FF; m2.K = FF;
    hipLaunchKernelGGL(gemm_k2, dim3(656), dim3(256), 0, stream, m2);
    hipLaunchKernelGGL(k_combine, dim3(TOK), dim3(256), 0, stream, Y, gates, tokpos, outp);
  };
  run_moe(g2, be2, Wr1, br1, Wn1, bn1, noise1, W1a, b1a, W2a, b2a, out_first);
  run_moe(g3, be3, Wr2, br2, Wn2, bn2, noise2, W1b, b1b, W2b, b2b, out_second);

  hipLaunchKernelGGL(k_feat1, dim3(8, 8), dim3(256), 0, stream, out_second, fpart);
  hipLaunchKernelGGL(k_feat2, dim3(32), dim3(256), 0, stream, fpart, feat);
  hipLaunchKernelGGL(k_cls, dim3(80), dim3(64), 0, stream, feat, Wc, bc, cls);
}

// Round 11
// 1222.125 us; speedup vs baseline: 1.0256x; 1.0256x over previous
//
#include <hip/hip_runtime.h>
#include <cstdint>

typedef unsigned short u16;
typedef __attribute__((ext_vector_type(8))) __bf16 bf16x8;
typedef __attribute__((ext_vector_type(4))) float f32x4;

#define TOK 4096
#define DM  1024
#define EXP 8
#define FF  4096
#define SEQ 512
#define NH  8
#define HD  128
#define JOBCAP 18432

__device__ __forceinline__ u16 f2bf(float f) {
  union { float f; unsigned int u; } v; v.f = f;
  unsigned int u = v.u;
  u += 0x7FFFu + ((u >> 16) & 1u);   // round-to-nearest-even
  return (u16)(u >> 16);
}
__device__ __forceinline__ float bf2f(u16 h) {
  union { unsigned int u; float f; } v; v.u = ((unsigned int)h) << 16; return v.f;
}

// async global->LDS, 16B per lane; dest = wave-uniform base + lane*16
__device__ __forceinline__ void gl_lds16(const u16* g, u16* l) {
  __builtin_amdgcn_global_load_lds(
      (const __attribute__((address_space(1))) unsigned int*)g,
      (__attribute__((address_space(3))) unsigned int*)l, 16, 0, 0);
}

// ---------------- embed gather ----------------
__global__ void k_embed(const int* __restrict__ ids, const float* __restrict__ emb,
                        float* __restrict__ x) {
  int t = blockIdx.x;
  int id = ids[t];
  const float4* src = (const float4*)(emb + (size_t)id * DM);
  float4* dst = (float4*)(x + (size_t)t * DM);
  dst[threadIdx.x] = src[threadIdx.x];
}

// ---------------- layernorm -> bf16 (MoE path) ----------------
__global__ void k_ln(const float* __restrict__ in, const float* __restrict__ g,
                     const float* __restrict__ be, u16* __restrict__ obf) {
  int t = blockIdx.x, tid = threadIdx.x;
  float4 v = ((const float4*)(in + (size_t)t * DM))[tid];
  float s = v.x + v.y + v.z + v.w;
  float sq = v.x*v.x + v.y*v.y + v.z*v.z + v.w*v.w;
  for (int o = 32; o; o >>= 1) { s += __shfl_down(s, o); sq += __shfl_down(sq, o); }
  __shared__ float ss[4], sqs[4];
  if ((tid & 63) == 0) { ss[tid >> 6] = s; sqs[tid >> 6] = sq; }
  __syncthreads();
  s  = ss[0] + ss[1] + ss[2] + ss[3];
  sq = sqs[0] + sqs[1] + sqs[2] + sqs[3];
  float mean = s * (1.f / DM);
  float var  = sq * (1.f / DM) - mean * mean;
  float rstd = rsqrtf(var + 1e-5f);
  float4 gg = ((const float4*)g)[tid];
  float4 bb = ((const float4*)be)[tid];
  ushort4 u;
  u.x = f2bf((v.x - mean) * rstd * gg.x + bb.x);
  u.y = f2bf((v.y - mean) * rstd * gg.y + bb.y);
  u.z = f2bf((v.z - mean) * rstd * gg.z + bb.z);
  u.w = f2bf((v.w - mean) * rstd * gg.w + bb.w);
  ((ushort4*)(obf + (size_t)t * DM))[tid] = u;
}

// ---------------- layernorm -> hi/lo bf16 pair (attention path) ----------------
__global__ void k_ln2(const float* __restrict__ in, const float* __restrict__ g,
                      const float* __restrict__ be, u16* __restrict__ oh,
                      u16* __restrict__ ol) {
  int t = blockIdx.x, tid = threadIdx.x;
  float4 v = ((const float4*)(in + (size_t)t * DM))[tid];
  float s = v.x + v.y + v.z + v.w;
  float sq = v.x*v.x + v.y*v.y + v.z*v.z + v.w*v.w;
  for (int o = 32; o; o >>= 1) { s += __shfl_down(s, o); sq += __shfl_down(sq, o); }
  __shared__ float ss[4], sqs[4];
  if ((tid & 63) == 0) { ss[tid >> 6] = s; sqs[tid >> 6] = sq; }
  __syncthreads();
  s  = ss[0] + ss[1] + ss[2] + ss[3];
  sq = sqs[0] + sqs[1] + sqs[2] + sqs[3];
  float mean = s * (1.f / DM);
  float var  = sq * (1.f / DM) - mean * mean;
  float rstd = rsqrtf(var + 1e-5f);
  float4 gg = ((const float4*)g)[tid];
  float4 bb = ((const float4*)be)[tid];
  float o4[4];
  o4[0] = (v.x - mean) * rstd * gg.x + bb.x;
  o4[1] = (v.y - mean) * rstd * gg.y + bb.y;
  o4[2] = (v.z - mean) * rstd * gg.z + bb.z;
  o4[3] = (v.w - mean) * rstd * gg.w + bb.w;
  ushort4 uh, ul;
  u16* ph = (u16*)&uh; u16* pl = (u16*)&ul;
  #pragma unroll
  for (int i = 0; i < 4; i++) {
    u16 hi = f2bf(o4[i]); ph[i] = hi; pl[i] = f2bf(o4[i] - bf2f(hi));
  }
  ((ushort4*)(oh + (size_t)t * DM))[tid] = uh;
  ((ushort4*)(ol + (size_t)t * DM))[tid] = ul;
}

// ---------------- transpose f32 [K,N] -> hi/lo bf16 [N,K] ----------------
__global__ void k_tcvt_split(const float* __restrict__ src, u16* __restrict__ dh,
                             u16* __restrict__ dl, int K, int N) {
  __shared__ float t[32][33];
  int k0 = blockIdx.x * 32, n0 = blockIdx.y * 32;
  int tx = threadIdx.x, ty = threadIdx.y;
  #pragma unroll
  for (int i = 0; i < 4; i++) t[ty + 8*i][tx] = src[(size_t)(k0 + ty + 8*i) * N + n0 + tx];
  __syncthreads();
  int u = ty * 32 + tx;
  int r = u >> 3, kq = u & 7;
  ushort4 oh, ol;
  u16* ph = (u16*)&oh; u16* pl = (u16*)&ol;
  #pragma unroll
  for (int i = 0; i < 4; i++) {
    float v = t[kq*4+i][r];
    u16 hi = f2bf(v); ph[i] = hi; pl[i] = f2bf(v - bf2f(hi));
  }
  *(ushort4*)&dh[(size_t)(n0 + r) * K + k0 + kq*4] = oh;
  *(ushort4*)&dl[(size_t)(n0 + r) * K + k0 + kq*4] = ol;
}

// ---------------- transpose f32 [K,N] -> bf16 [N,K], z-batched (MoE weights) ----------------
__global__ void k_tcvt(const float* __restrict__ src, u16* __restrict__ dst, int K, int N) {
  __shared__ float t[32][33];
  size_t zoff = (size_t)blockIdx.z * K * N;
  src += zoff;
  u16* d = dst + zoff;
  int k0 = blockIdx.x * 32, n0 = blockIdx.y * 32;
  int tx = threadIdx.x, ty = threadIdx.y;
  #pragma unroll
  for (int i = 0; i < 4; i++) t[ty + 8*i][tx] = src[(size_t)(k0 + ty + 8*i) * N + n0 + tx];
  __syncthreads();
  int u = ty * 32 + tx;
  int r = u >> 3, kq = u & 7;
  ushort4 o;
  o.x = f2bf(t[kq*4+0][r]); o.y = f2bf(t[kq*4+1][r]);
  o.z = f2bf(t[kq*4+2][r]); o.w = f2bf(t[kq*4+3][r]);
  *(ushort4*)&d[(size_t)(n0 + r) * K + k0 + kq*4] = o;
}

// ---------------- causal softmax f32 -> att hi/lo bf16 in place ----------------
__global__ void k_softmax_h(float* __restrict__ scores) {
  int q = blockIdx.x, bh = blockIdx.y, tid = threadIdx.x;
  float* row = scores + ((size_t)bh * 512 + q) * 512;
  u16* orow = (u16*)row;
  const float scale = 0.088388347648318447f; // 128^-0.5
  int j0 = tid * 2;
  float v0 = -1e30f, v1 = -1e30f;
  if (j0 <= q)     v0 = row[j0] * scale;
  if (j0 + 1 <= q) v1 = row[j0 + 1] * scale;
  float m = fmaxf(v0, v1);
  for (int o = 32; o; o >>= 1) m = fmaxf(m, __shfl_down(m, o));
  __shared__ float sm[4], ssum[4];
  if ((tid & 63) == 0) sm[tid >> 6] = m;
  __syncthreads();
  m = fmaxf(fmaxf(sm[0], sm[1]), fmaxf(sm[2], sm[3]));
  float p0 = (j0 <= q)     ? expf(v0 - m) : 0.f;
  float p1 = (j0 + 1 <= q) ? expf(v1 - m) : 0.f;
  float s = p0 + p1;
  for (int o = 32; o; o >>= 1) s += __shfl_down(s, o);
  if ((tid & 63) == 0) ssum[tid >> 6] = s;
  __syncthreads();
  s = ssum[0] + ssum[1] + ssum[2] + ssum[3];
  float inv = 1.f / s;
  float pi0 = p0 * inv, pi1 = p1 * inv;
  u16 h0 = f2bf(pi0), h1 = f2bf(pi1);
  orow[j0]       = h0; orow[j0 + 1]       = h1;
  orow[512 + j0] = f2bf(pi0 - bf2f(h0));
  orow[512 + j0 + 1] = f2bf(pi1 - bf2f(h1));
}

// ---------------- split-bf16 3-pass MFMA GEMM (attention path) ----------------
constexpr int HOP_QKV    = 0;
constexpr int HOP_SCORES = 1;
constexpr int HOP_PV     = 2;
constexpr int HOP_PROJ   = 3;

struct GemmHArgs {
  const u16 *Ah, *Al, *Bh, *Bl;
  u16 *D0h, *D0l, *D1h, *D1l, *D2h, *D2l;
  float *Cf;
  const float *bias, *resid, *pos;
  int lda, ldb, K;
};

template<int OP>
__launch_bounds__(256)
__global__ void gemm_h(GemmHArgs p) {
  int bx, by, z;
  if constexpr (OP == HOP_QKV) {
    int bid = blockIdx.x; int xcd = bid & 7, slot = bid >> 3;
    by = xcd * 3 + (slot >> 5); bx = slot & 31; z = 0;
  } else if constexpr (OP == HOP_PROJ) {
    int bid = blockIdx.x; by = bid & 7; bx = bid >> 3; z = 0;
  } else if constexpr (OP == HOP_SCORES) { // dense triangular: 10 tiles x 64 bh
    int bid = blockIdx.x; z = bid / 10; int t = bid % 10;
    bx = (t >= 6) ? 3 : (t >= 3) ? 2 : (t >= 1) ? 1 : 0;
    by = t - ((bx * (bx + 1)) >> 1);
  } else {
    bx = blockIdx.x; by = blockIdx.y; z = blockIdx.z;
  }

  const u16 *Ahb, *Alb, *Bhb, *Blb;
  if constexpr (OP == HOP_SCORES) {
    size_t off = (size_t)(z >> 3) * 524288 + (size_t)(z & 7) * 128;
    Ahb = p.Ah + off; Alb = p.Al + off; Bhb = p.Bh + off; Blb = p.Bl + off;
  } else if constexpr (OP == HOP_PV) {
    size_t aoff = (size_t)z * 524288;
    Ahb = p.Ah + aoff; Alb = p.Ah + aoff + 512;
    size_t boff = (size_t)z * 65536;
    Bhb = p.Bh + boff; Blb = p.Bl + boff;
  } else {
    Ahb = p.Ah; Alb = p.Al; Bhb = p.Bh; Blb = p.Bl;
  }

  int kmax = p.K;
  if constexpr (OP == HOP_PV) { int lim = bx * 128 + 128; kmax = lim < p.K ? lim : p.K; }
  int nt = kmax >> 5;

  __shared__ __align__(16) u16 As[2 * 4096];
  __shared__ __align__(16) u16 Bs[2 * 4096];

  int tid = threadIdx.x, lane = tid & 63, wid = tid >> 6;
  int srow = wid * 16 + (lane >> 2), skoff = (lane & 3) * 8;
  int lo0 = (wid * 16) * 32, lo1 = ((wid + 4) * 16) * 32;
  int wr = wid >> 1, wc = wid & 1, fm = lane & 15, fk = (lane >> 4) * 8;

  f32x4 acc[4][4] = {};
  const size_t lda = p.lda, ldb = p.ldb;

  #pragma unroll 1
  for (int pass = 0; pass < 3; ++pass) {
    const u16* Ab = (pass < 2) ? Ahb : Alb;
    const u16* Bb = (pass & 1) ? Blb : Bhb;
    const u16* aptr0 = Ab + (size_t)(bx * 128 + srow) * lda + skoff;
    const u16* aptr1 = Ab + (size_t)(bx * 128 + 64 + srow) * lda + skoff;
    const u16* bptr0 = Bb + (size_t)(by * 128 + srow) * ldb + skoff;
    const u16* bptr1 = Bb + (size_t)(by * 128 + 64 + srow) * ldb + skoff;

    gl_lds16(aptr0, &As[lo0]); gl_lds16(aptr1, &As[lo1]);
    gl_lds16(bptr0, &Bs[lo0]); gl_lds16(bptr1, &Bs[lo1]);
    __syncthreads();
    int cur = 0;
    for (int t = 0; t < nt; ++t) {
      if (t + 1 < nt) {
        int nxt = (cur ^ 1) * 4096;
        int k0 = (t + 1) * 32;
        gl_lds16(aptr0 + k0, &As[nxt + lo0]); gl_lds16(aptr1 + k0, &As[nxt + lo1]);
        gl_lds16(bptr0 + k0, &Bs[nxt + lo0]); gl_lds16(bptr1 + k0, &Bs[nxt + lo1]);
      }
      int cb = cur * 4096;
      bf16x8 af[4], bfr[4];
      #pragma unroll
      for (int i = 0; i < 4; ++i) {
        af[i]  = *(const bf16x8*)&As[cb + (wr * 64 + i * 16 + fm) * 32 + fk];
        bfr[i] = *(const bf16x8*)&Bs[cb + (wc * 64 + i * 16 + fm) * 32 + fk];
      }
      #pragma unroll
      for (int mi = 0; mi < 4; ++mi)
        #pragma unroll
        for (int ni = 0; ni < 4; ++ni)
          acc[mi][ni] = __builtin_amdgcn_mfma_f32_16x16x32_bf16(af[mi], bfr[ni], acc[mi][ni], 0, 0, 0);
      __syncthreads();
      cur ^= 1;
    }
  }

  int rb = (lane >> 4) * 4, cl = lane & 15;
  #pragma unroll
  for (int mi = 0; mi < 4; ++mi)
    #pragma unroll
    for (int ni = 0; ni < 4; ++ni)
      #pragma unroll
      for (int j = 0; j < 4; ++j) {
        int m = bx * 128 + wr * 64 + mi * 16 + rb + j;
        int n = by * 128 + wc * 64 + ni * 16 + cl;
        float v = acc[mi][ni][j];
        if constexpr (OP == HOP_QKV) {
          u16 hi = f2bf(v); u16 lo = f2bf(v - bf2f(hi));
          int sel = n >> 10, nn = n & 1023;
          if (sel == 0) {
            p.D0h[(size_t)m * DM + nn] = hi; p.D0l[(size_t)m * DM + nn] = lo;
          } else if (sel == 1) {
            p.D1h[(size_t)m * DM + nn] = hi; p.D1l[(size_t)m * DM + nn] = lo;
          } else {
            size_t idx = (size_t)((m >> 9) * 8 + (nn >> 7)) * 65536 + (size_t)(nn & 127) * 512 + (m & 511);
            p.D2h[idx] = hi; p.D2l[idx] = lo;
          }
        } else if constexpr (OP == HOP_SCORES) {
          p.Cf[(size_t)z * 262144 + (size_t)m * 512 + n] = v;
        } else if constexpr (OP == HOP_PV) {
          u16 hi = f2bf(v); u16 lo = f2bf(v - bf2f(hi));
          size_t idx = (size_t)(z >> 3) * 524288 + (size_t)m * 1024 + (size_t)(z & 7) * 128 + n;
          p.D0h[idx] = hi; p.D0l[idx] = lo;
        } else { // HOP_PROJ
          size_t idx = (size_t)m * 1024 + n;
          p.Cf[idx] = v + p.bias[n] + p.resid[idx] + p.pos[(size_t)(m & 511) * 1024 + n];
        }
      }
}

// ---------------- bf16 MFMA 128x128 TN GEMM, 2-phase dbuf, 16-expert merged (MoE) ----------------
constexpr int OP_MOE1 = 0; // gathered A rows (joblist -> xlnb[2*TOK]), bf16 C=relu(acc+b1)
constexpr int OP_MOE2 = 1; // contiguous padded A rows, f32 C=acc+b2

struct GemmArgs {
  const u16* A; const u16* B; void* C;
  const float* b1a; const float* b1b;   // per-half bias arrays (8 experts each)
  const int* joblist; const int* seg;   // seg[0..16]
  int lda, ldb, K;
};

template<int OP>
__launch_bounds__(256)
__global__ void gemm_k(GemmArgs p) {
  int bid = blockIdx.x;
  int xcd = bid & 7, slot = bid >> 3;
  int bx, by;
  if constexpr (OP == OP_MOE1) {
    // grid 4608 = 8 x 576: XCD c owns by in [4c,4c+4); bx 0..143
    by = xcd * 4 + (slot & 3);
    bx = slot >> 2;
  } else {
    // grid 1152 = 8 x 144: XCD c owns bx in [18c,18c+18); by 0..7
    bx = xcd * 18 + (slot >> 3);
    by = slot & 7;
  }
  int r0g = bx * 128;
  if (r0g >= p.seg[16]) return;
  int z = 0;
  #pragma unroll
  for (int e = 1; e < 16; ++e) z += (r0g >= p.seg[e]) ? 1 : 0;
  const u16* Bbase = p.B + (size_t)z * 4194304;
  const float* bias = (z < 8) ? p.b1a + (size_t)z * (OP == OP_MOE1 ? FF : DM)
                              : p.b1b + (size_t)(z - 8) * (OP == OP_MOE1 ? FF : DM);

  __shared__ __align__(16) u16 As[2 * 4096];
  __shared__ __align__(16) u16 Bs[2 * 4096];

  int tid = threadIdx.x;
  int lane = tid & 63, wid = tid >> 6;

  int srow = wid * 16 + (lane >> 2);
  int skoff = (lane & 3) * 8;

  const u16 *aptr0, *aptr1;
  if constexpr (OP == OP_MOE1) {
    int j0 = p.joblist[r0g + srow];
    int j1 = p.joblist[r0g + 64 + srow];
    aptr0 = p.A + (size_t)(j0 < 0 ? 0 : j0) * p.lda + skoff;
    aptr1 = p.A + (size_t)(j1 < 0 ? 0 : j1) * p.lda + skoff;
  } else {
    aptr0 = p.A + (size_t)(r0g + srow) * p.lda + skoff;
    aptr1 = p.A + (size_t)(r0g + 64 + srow) * p.lda + skoff;
  }
  const u16* bptr0 = Bbase + (size_t)(by * 128 + srow) * p.ldb + skoff;
  const u16* bptr1 = Bbase + (size_t)(by * 128 + 64 + srow) * p.ldb + skoff;

  int lo0 = (wid * 16) * 32;
  int lo1 = ((wid + 4) * 16) * 32;

  int wr = wid >> 1, wc = wid & 1;
  int fm = lane & 15;
  int fk = (lane >> 4) * 8;

  f32x4 acc[4][4] = {};
  int nt = p.K >> 5;

  gl_lds16(aptr0, &As[lo0]); gl_lds16(aptr1, &As[lo1]);
  gl_lds16(bptr0, &Bs[lo0]); gl_lds16(bptr1, &Bs[lo1]);
  __syncthreads();

  int cur = 0;
  for (int t = 0; t < nt; ++t) {
    if (t + 1 < nt) {
      int nxt = (cur ^ 1) * 4096;
      int k0 = (t + 1) * 32;
      gl_lds16(aptr0 + k0, &As[nxt + lo0]); gl_lds16(aptr1 + k0, &As[nxt + lo1]);
      gl_lds16(bptr0 + k0, &Bs[nxt + lo0]); gl_lds16(bptr1 + k0, &Bs[nxt + lo1]);
    }
    int cb = cur * 4096;
    bf16x8 af[4], bfr[4];
    #pragma unroll
    for (int i = 0; i < 4; ++i) {
      af[i]  = *(const bf16x8*)&As[cb + (wr * 64 + i * 16 + fm) * 32 + fk];
      bfr[i] = *(const bf16x8*)&Bs[cb + (wc * 64 + i * 16 + fm) * 32 + fk];
    }
    #pragma unroll
    for (int mi = 0; mi < 4; ++mi)
      #pragma unroll
      for (int ni = 0; ni < 4; ++ni)
        acc[mi][ni] = __builtin_amdgcn_mfma_f32_16x16x32_bf16(af[mi], bfr[ni], acc[mi][ni], 0, 0, 0);
    __syncthreads();
    cur ^= 1;
  }

  int rb = (lane >> 4) * 4;
  int cl = lane & 15;
  #pragma unroll
  for (int mi = 0; mi < 4; ++mi)
    #pragma unroll
    for (int ni = 0; ni < 4; ++ni)
      #pragma unroll
      for (int j = 0; j < 4; ++j) {
        int m = r0g + wr * 64 + mi * 16 + rb + j;
        int n = by * 128 + wc * 64 + ni * 16 + cl;
        float v = acc[mi][ni][j];
        if constexpr (OP == OP_MOE1) {
          float t2 = v + bias[n];
          t2 = t2 > 0.f ? t2 : 0.f;
          ((u16*)p.C)[(size_t)m * FF + n] = f2bf(t2);
        } else {
          ((float*)p.C)[(size_t)m * DM + n] = v + bias[n];
        }
      }
}

// ---------------- router: inline fp32 LN + logits + noisy top-2 + gates ----------------
__global__ void k_router(const float* __restrict__ xin, const float* __restrict__ g,
                         const float* __restrict__ be,
                         const float* __restrict__ Wr, const float* __restrict__ br,
                         const float* __restrict__ Wn, const float* __restrict__ bn,
                         const float* __restrict__ noise,
                         float* __restrict__ gates, int* __restrict__ topidx) {
  int t = blockIdx.x, tid = threadIdx.x;
  float4 v = ((const float4*)(xin + (size_t)t * DM))[tid];
  float s = v.x + v.y + v.z + v.w;
  float sq = v.x*v.x + v.y*v.y + v.z*v.z + v.w*v.w;
  for (int o = 32; o; o >>= 1) { s += __shfl_down(s, o); sq += __shfl_down(sq, o); }
  __shared__ float ss[4], sqs[4];
  if ((tid & 63) == 0) { ss[tid >> 6] = s; sqs[tid >> 6] = sq; }
  __syncthreads();
  s  = ss[0] + ss[1] + ss[2] + ss[3];
  sq = sqs[0] + sqs[1] + sqs[2] + sqs[3];
  float mean = s * (1.f / DM);
  float var  = sq * (1.f / DM) - mean * mean;
  float rstd = rsqrtf(var + 1e-5f);
  float4 gg = ((const float4*)g)[tid];
  float4 bb = ((const float4*)be)[tid];
  float xl[4];
  xl[0] = (v.x - mean) * rstd * gg.x + bb.x;
  xl[1] = (v.y - mean) * rstd * gg.y + bb.y;
  xl[2] = (v.z - mean) * rstd * gg.z + bb.z;
  xl[3] = (v.w - mean) * rstd * gg.w + bb.w;
  float pl[8], pn[8];
  #pragma unroll
  for (int e = 0; e < 8; e++) { pl[e] = 0.f; pn[e] = 0.f; }
  #pragma unroll
  for (int j = 0; j < 4; j++) {
    int d = tid * 4 + j;
    float xv = xl[j];
    const float4* wr = (const float4*)(Wr + (size_t)d * 8);
    const float4* wn = (const float4*)(Wn + (size_t)d * 8);
    float4 a0 = wr[0], a1 = wr[1], c0 = wn[0], c1 = wn[1];
    pl[0] += xv * a0.x; pl[1] += xv * a0.y; pl[2] += xv * a0.z; pl[3] += xv * a0.w;
    pl[4] += xv * a1.x; pl[5] += xv * a1.y; pl[6] += xv * a1.z; pl[7] += xv * a1.w;
    pn[0] += xv * c0.x; pn[1] += xv * c0.y; pn[2] += xv * c0.z; pn[3] += xv * c0.w;
    pn[4] += xv * c1.x; pn[5] += xv * c1.y; pn[6] += xv * c1.z; pn[7] += xv * c1.w;
  }
  for (int o = 32; o; o >>= 1) {
    #pragma unroll
    for (int e = 0; e < 8; e++) { pl[e] += __shfl_down(pl[e], o); pn[e] += __shfl_down(pn[e], o); }
  }
  __shared__ float sl[4][8], sn[4][8];
  if ((tid & 63) == 0) {
    int w = tid >> 6;
    #pragma unroll
    for (int e = 0; e < 8; e++) { sl[w][e] = pl[e]; sn[w][e] = pn[e]; }
  }
  __syncthreads();
  if (tid == 0) {
    float noisy[8];
    #pragma unroll
    for (int e = 0; e < 8; e++) {
      float l  = sl[0][e] + sl[1][e] + sl[2][e] + sl[3][e] + br[e];
      float nn = sn[0][e] + sn[1][e] + sn[2][e] + sn[3][e] + bn[e];
      float sp = (nn > 20.f) ? nn : log1pf(expf(nn));
      noisy[e] = l + noise[(size_t)t * 8 + e] * sp;
    }
    int i0 = 0;
    for (int e = 1; e < 8; e++) if (noisy[e] > noisy[i0]) i0 = e;
    int i1 = (i0 == 0) ? 1 : 0;
    for (int e = 0; e < 8; e++) if (e != i0 && noisy[e] > noisy[i1]) i1 = e;
    float e1 = expf(noisy[i1] - noisy[i0]);
    float zz = 1.f + e1;
    gates[t * 2] = 1.f / zz; gates[t * 2 + 1] = e1 / zz;
    topidx[t * 2] = i0; topidx[t * 2 + 1] = i1;
  }
}

// ---------------- MoE bookkeeping (16-expert merged) ----------------
__global__ void k_moe_init(int* cnt, int* cnt2, int* joblist) {
  int i = blockIdx.x * 256 + threadIdx.x;
  if (i < JOBCAP) joblist[i] = -1;
  if (i < 16) { cnt[i] = 0; cnt2[i] = 0; }
}
__global__ void k_moe_count(const int* __restrict__ topidx, int* __restrict__ cnt) {
  int t = blockIdx.x * 256 + threadIdx.x;     // global token 0..2*TOK
  if (t >= 2 * TOK) return;
  int lo = (t >= TOK) ? 8 : 0;
  atomicAdd(&cnt[topidx[t * 2] + lo], 1);
  atomicAdd(&cnt[topidx[t * 2 + 1] + lo], 1);
}
__global__ void k_moe_offsets(const int* __restrict__ cnt, int* __restrict__ seg) {
  if (threadIdx.x == 0) {
    int o = 0;
    for (int e = 0; e < 16; e++) { seg[e] = o; o += (cnt[e] + 127) & ~127; }
    seg[16] = o;
  }
}
__global__ void k_moe_scatter(const int* __restrict__ topidx, int* __restrict__ cnt2,
                              const int* __restrict__ seg, int* __restrict__ joblist,
                              int* __restrict__ tokpos) {
  int t = blockIdx.x * 256 + threadIdx.x;
  if (t >= 2 * TOK) return;
  int lo = (t >= TOK) ? 8 : 0;
  #pragma unroll
  for (int s = 0; s < 2; s++) {
    int e = topidx[t * 2 + s] + lo;
    int p = atomicAdd(&cnt2[e], 1);
    int pos = seg[e] + p;
    joblist[pos] = t;                 // global row into xlnb[2*TOK]
    tokpos[t * 2 + s] = pos;
  }
}
__global__ void k_combine(const float* __restrict__ y, const float* __restrict__ gates,
                          const int* __restrict__ tokpos, float* __restrict__ out) {
  int t = blockIdx.x, tid = threadIdx.x;
  int p0 = tokpos[t * 2], p1 = tokpos[t * 2 + 1];
  float g0 = gates[t * 2], g1 = gates[t * 2 + 1];
  float4 a = ((const float4*)(y + (size_t)p0 * DM))[tid];
  float4 b = ((const float4*)(y + (size_t)p1 * DM))[tid];
  float4 o;
  o.x = g0 * a.x + g1 * b.x; o.y = g0 * a.y + g1 * b.y;
  o.z = g0 * a.z + g1 * b.z; o.w = g0 * a.w + g1 * b.w;
  ((float4*)(out + (size_t)t * DM))[tid] = o;
}

// ---------------- feature mean (two-stage) + classifier ----------------
__global__ void k_feat1(const float* __restrict__ second, float* __restrict__ part) {
  int b = blockIdx.x, c = blockIdx.y, tid = threadIdx.x;
  const float* p = second + ((size_t)b * SEQ + (size_t)c * 64) * DM;
  float4 s = {0.f, 0.f, 0.f, 0.f};
  for (int j = 0; j < 64; ++j) {
    float4 v = ((const float4*)(p + (size_t)j * DM))[tid];
    s.x += v.x; s.y += v.y; s.z += v.z; s.w += v.w;
  }
  ((float4*)(part + (size_t)(b * 8 + c) * DM))[tid] = s;
}
__global__ void k_feat2(const float* __restrict__ part, float* __restrict__ feat) {
  int i = blockIdx.x * 256 + threadIdx.x;
  int b = i >> 10, d = i & 1023;
  float s = 0.f;
  #pragma unroll
  for (int c = 0; c < 8; ++c) s += part[(size_t)(b * 8 + c) * DM + d];
  feat[i] = s * (1.f / SEQ);
}
__global__ void k_cls(const float* __restrict__ feat, const float* __restrict__ Wc,
                      const float* __restrict__ bc, float* __restrict__ cls) {
  int o = blockIdx.x; int b = o / 10, n = o % 10; int l = threadIdx.x;
  float s = 0.f;
  for (int d = l; d < DM; d += 64) s += feat[b * DM + d] * Wc[(size_t)d * 10 + n];
  for (int off = 32; off; off >>= 1) s += __shfl_down(s, off);
  if (l == 0) cls[o] = s + bc[n];
}

// ---------------- launch ----------------
extern "C" void kernel_launch(void* const* d_in, const int* in_sizes, int n_in,
                              void* d_out, int out_size, void* d_ws, size_t ws_size,
                              hipStream_t stream) {
  const int*   ids    = (const int*)d_in[0];
  const float* emb    = (const float*)d_in[2];
  const float* pos    = (const float*)d_in[3];
  const float* Wq     = (const float*)d_in[4];
  const float* Wk     = (const float*)d_in[5];
  const float* Wv     = (const float*)d_in[6];
  const float* Wo     = (const float*)d_in[7];
  const float* bo     = (const float*)d_in[8];
  const float* g1     = (const float*)d_in[9];
  const float* be1    = (const float*)d_in[10];
  const float* g2     = (const float*)d_in[11];
  const float* be2    = (const float*)d_in[12];
  const float* g3     = (const float*)d_in[13];
  const float* be3    = (const float*)d_in[14];
  const float* Wr1    = (const float*)d_in[15];
  const float* br1    = (const float*)d_in[16];
  const float* Wn1    = (const float*)d_in[17];
  const float* bn1    = (const float*)d_in[18];
  const float* W1a    = (const float*)d_in[19];
  const float* b1a    = (const float*)d_in[20];
  const float* W2a    = (const float*)d_in[21];
  const float* b2a    = (const float*)d_in[22];
  const float* Wr2    = (const float*)d_in[23];
  const float* br2    = (const float*)d_in[24];
  const float* Wn2    = (const float*)d_in[25];
  const float* bn2    = (const float*)d_in[26];
  const float* W1b    = (const float*)d_in[27];
  const float* b1b    = (const float*)d_in[28];
  const float* W2b    = (const float*)d_in[29];
  const float* b2b    = (const float*)d_in[30];
  const float* noise1 = (const float*)d_in[31];
  const float* noise2 = (const float*)d_in[32];
  const float* Wc     = (const float*)d_in[33];
  const float* bc     = (const float*)d_in[34];

  char* wsp = (char*)d_ws; size_t off = 0;
  auto alloc = [&](size_t bytes) -> void* {
    void* p = wsp + off; off += (bytes + 255) & ~(size_t)255; return p;
  };
  char*  G     = (char*)alloc(360710144);              // phase-overlaid big region (344MB)
  float* x     = (float*)alloc((size_t)TOK * DM * 4);
  float* x2    = (float*)alloc((size_t)TOK * DM * 4);
  u16*   xlnb  = (u16*)alloc((size_t)2 * TOK * DM * 2);   // both layers' LN
  float* gates  = (float*)alloc(2 * TOK * 2 * 4);
  int*   topidx = (int*)alloc(2 * TOK * 2 * 4);
  int*   cnt    = (int*)alloc(16 * 4);
  int*   cnt2   = (int*)alloc(16 * 4);
  int*   seg    = (int*)alloc(24 * 4);
  int*   joblist= (int*)alloc(JOBCAP * 4);
  int*   tokpos = (int*)alloc(2 * TOK * 2 * 4);
  float* fpart  = (float*)alloc(64 * DM * 4);
  (void)ws_size; (void)in_sizes; (void)n_in; (void)out_size;

  // attention-phase views (~164MB of G)
  u16* WQKVTh = (u16*)(G + 0);
  u16* WQKVTl = (u16*)(G + 6291456);
  u16* WOTh   = (u16*)(G + 12582912);
  u16* WOTl   = (u16*)(G + 14680064);
  u16* XLNH   = (u16*)(G + 16777216);
  u16* XLNL   = (u16*)(G + 25165824);
  u16* QH     = (u16*)(G + 33554432);
  u16* QL     = (u16*)(G + 41943040);
  u16* KH     = (u16*)(G + 50331648);
  u16* KL     = (u16*)(G + 58720256);
  u16* VTh    = (u16*)(G + 67108864);
  u16* VTl    = (u16*)(G + 75497472);
  u16* OH     = (u16*)(G + 83886080);
  u16* OL     = (u16*)(G + 92274688);
  float* SC   = (float*)(G + 100663296);  // [64][512][512] f32 -> att hi/lo in place
  // moe-phase views (344MB of G; attention buffers dead by then)
  u16*   H    = (u16*)(G + 0);            // [18432][4096] bf16 (151MB)
  float* Y    = (float*)(G + 150994944);  // [18432][1024] f32 (75.5MB)
  u16*   WBUF = (u16*)(G + 226492416);    // 16 experts' weights bf16 (128MB)

  float* out_first  = (float*)d_out;
  float* out_second = out_first + (size_t)TOK * DM;
  float* feat       = out_first + (size_t)2 * TOK * DM;
  float* cls        = feat + 8 * DM;

  dim3 tb(32, 8);
  // ---- attention phase: split-bf16 3-pass ----
  hipLaunchKernelGGL(k_tcvt_split, dim3(32, 32), tb, 0, stream, Wq, WQKVTh,            WQKVTl,            DM, DM);
  hipLaunchKernelGGL(k_tcvt_split, dim3(32, 32), tb, 0, stream, Wk, WQKVTh + 1048576,  WQKVTl + 1048576,  DM, DM);
  hipLaunchKernelGGL(k_tcvt_split, dim3(32, 32), tb, 0, stream, Wv, WQKVTh + 2097152,  WQKVTl + 2097152,  DM, DM);
  hipLaunchKernelGGL(k_tcvt_split, dim3(32, 32), tb, 0, stream, Wo, WOTh,              WOTl,              DM, DM);
  hipLaunchKernelGGL(k_embed, dim3(TOK), dim3(256), 0, stream, ids, emb, x);
  hipLaunchKernelGGL(k_ln2, dim3(TOK), dim3(256), 0, stream, x, g1, be1, XLNH, XLNL);

  GemmHArgs qa{};
  qa.Ah = XLNH; qa.Al = XLNL; qa.Bh = WQKVTh; qa.Bl = WQKVTl;
  qa.D0h = QH; qa.D0l = QL; qa.D1h = KH; qa.D1l = KL; qa.D2h = VTh; qa.D2l = VTl;
  qa.lda = DM; qa.ldb = DM; qa.K = DM;
  hipLaunchKernelGGL(gemm_h<HOP_QKV>, dim3(768), dim3(256), 0, stream, qa);

  GemmHArgs sa{};
  sa.Ah = QH; sa.Al = QL; sa.Bh = KH; sa.Bl = KL; sa.Cf = SC;
  sa.lda = DM; sa.ldb = DM; sa.K = HD;
  hipLaunchKernelGGL(gemm_h<HOP_SCORES>, dim3(640), dim3(256), 0, stream, sa);
  hipLaunchKernelGGL(k_softmax_h, dim3(SEQ, 64), dim3(256), 0, stream, SC);

  GemmHArgs pa{};
  pa.Ah = (const u16*)SC; pa.Bh = VTh; pa.Bl = VTl;
  pa.D0h = OH; pa.D0l = OL;
  pa.lda = 1024; pa.ldb = 512; pa.K = SEQ;
  hipLaunchKernelGGL(gemm_h<HOP_PV>, dim3(4, 1, 64), dim3(256), 0, stream, pa);

  GemmHArgs pj{};
  pj.Ah = OH; pj.Al = OL; pj.Bh = WOTh; pj.Bl = WOTl; pj.Cf = x2;
  pj.bias = bo; pj.resid = x; pj.pos = pos;
  pj.lda = DM; pj.ldb = DM; pj.K = DM;
  hipLaunchKernelGGL(gemm_h<HOP_PROJ>, dim3(256), dim3(256), 0, stream, pj);

  // ---- MoE phase: both layers merged into one 16-expert batch ----
  hipLaunchKernelGGL(k_ln, dim3(TOK), dim3(256), 0, stream, x2, g2, be2, xlnb);
  hipLaunchKernelGGL(k_ln, dim3(TOK), dim3(256), 0, stream, x2, g3, be3, xlnb + (size_t)TOK * DM);
  hipLaunchKernelGGL(k_router, dim3(TOK), dim3(256), 0, stream, x2, g2, be2, Wr1, br1, Wn1, bn1, noise1, gates, topidx);
  hipLaunchKernelGGL(k_router, dim3(TOK), dim3(256), 0, stream, x2, g3, be3, Wr2, br2, Wn2, bn2, noise2,
                     gates + (size_t)TOK * 2, topidx + (size_t)TOK * 2);
  hipLaunchKernelGGL(k_moe_init, dim3(72), dim3(256), 0, stream, cnt, cnt2, joblist);
  hipLaunchKernelGGL(k_moe_count, dim3(32), dim3(256), 0, stream, topidx, cnt);
  hipLaunchKernelGGL(k_moe_offsets, dim3(1), dim3(64), 0, stream, cnt, seg);
  hipLaunchKernelGGL(k_moe_scatter, dim3(32), dim3(256), 0, stream, topidx, cnt2, seg, joblist, tokpos);

  hipLaunchKernelGGL(k_tcvt, dim3(32, 128, 8), tb, 0, stream, W1a, WBUF, DM, FF);
  hipLaunchKernelGGL(k_tcvt, dim3(32, 128, 8), tb, 0, stream, W1b, WBUF + (size_t)8 * DM * FF, DM, FF);
  GemmArgs m1{};
  m1.A = xlnb; m1.B = WBUF; m1.C = H; m1.b1a = b1a; m1.b1b = b1b;
  m1.joblist = joblist; m1.seg = seg;
  m1.lda = DM; m1.ldb = DM; m1.K = DM;
  hipLaunchKernelGGL(gemm_k<OP_MOE1>, dim3(4608), dim3(256), 0, stream, m1);

  hipLaunchKernelGGL(k_tcvt, dim3(128, 32, 8), tb, 0, stream, W2a, WBUF, FF, DM);
  hipLaunchKernelGGL(k_tcvt, dim3(128, 32, 8), tb, 0, stream, W2b, WBUF + (size_t)8 * DM * FF, FF, DM);
  GemmArgs m2{};
  m2.A = H; m2.B = WBUF; m2.C = Y; m2.b1a = b2a; m2.b1b = b2b;
  m2.joblist = joblist; m2.seg = seg;
  m2.lda = FF; m2.ldb = FF; m2.K = FF;
  hipLaunchKernelGGL(gemm_k<OP_MOE2>, dim3(1152), dim3(256), 0, stream, m2);

  hipLaunchKernelGGL(k_combine, dim3(TOK), dim3(256), 0, stream, Y, gates, tokpos, out_first);
  hipLaunchKernelGGL(k_combine, dim3(TOK), dim3(256), 0, stream, Y,
                     gates + (size_t)TOK * 2, tokpos + (size_t)TOK * 2, out_second);

  hipLaunchKernelGGL(k_feat1, dim3(8, 8), dim3(256), 0, stream, out_second, fpart);
  hipLaunchKernelGGL(k_feat2, dim3(32), dim3(256), 0, stream, fpart, feat);
  hipLaunchKernelGGL(k_cls, dim3(80), dim3(64), 0, stream, feat, Wc, bc, cls);
}

// Round 12
// 1178.805 us; speedup vs baseline: 1.0633x; 1.0367x over previous
//
#include <hip/hip_runtime.h>
#include <cstdint>

typedef unsigned short u16;
typedef __attribute__((ext_vector_type(8))) __bf16 bf16x8;
typedef __attribute__((ext_vector_type(4))) float f32x4;

#define TOK 4096
#define DM  1024
#define EXP 8
#define FF  4096
#define SEQ 512
#define NH  8
#define HD  128
#define JOBCAP 18432

__device__ __forceinline__ u16 f2bf(float f) {
  union { float f; unsigned int u; } v; v.f = f;
  unsigned int u = v.u;
  u += 0x7FFFu + ((u >> 16) & 1u);   // round-to-nearest-even
  return (u16)(u >> 16);
}
__device__ __forceinline__ float bf2f(u16 h) {
  union { unsigned int u; float f; } v; v.u = ((unsigned int)h) << 16; return v.f;
}

// async global->LDS, 16B per lane; dest = wave-uniform base + lane*16
__device__ __forceinline__ void gl_lds16(const u16* g, u16* l) {
  __builtin_amdgcn_global_load_lds(
      (const __attribute__((address_space(1))) unsigned int*)g,
      (__attribute__((address_space(3))) unsigned int*)l, 16, 0, 0);
}

// ---------------- embed gather ----------------
__global__ void k_embed(const int* __restrict__ ids, const float* __restrict__ emb,
                        float* __restrict__ x) {
  int t = blockIdx.x;
  int id = ids[t];
  const float4* src = (const float4*)(emb + (size_t)id * DM);
  float4* dst = (float4*)(x + (size_t)t * DM);
  dst[threadIdx.x] = src[threadIdx.x];
}

// ---------------- fused layernorm(bf16 out) + router (MoE path) ----------------
__global__ void k_lnrouter(const float* __restrict__ xin, const float* __restrict__ g,
                           const float* __restrict__ be,
                           const float* __restrict__ Wr, const float* __restrict__ br,
                           const float* __restrict__ Wn, const float* __restrict__ bn,
                           const float* __restrict__ noise,
                           u16* __restrict__ obf,
                           float* __restrict__ gates, int* __restrict__ topidx) {
  int t = blockIdx.x, tid = threadIdx.x;
  float4 v = ((const float4*)(xin + (size_t)t * DM))[tid];
  float s = v.x + v.y + v.z + v.w;
  float sq = v.x*v.x + v.y*v.y + v.z*v.z + v.w*v.w;
  for (int o = 32; o; o >>= 1) { s += __shfl_down(s, o); sq += __shfl_down(sq, o); }
  __shared__ float ss[4], sqs[4];
  if ((tid & 63) == 0) { ss[tid >> 6] = s; sqs[tid >> 6] = sq; }
  __syncthreads();
  s  = ss[0] + ss[1] + ss[2] + ss[3];
  sq = sqs[0] + sqs[1] + sqs[2] + sqs[3];
  float mean = s * (1.f / DM);
  float var  = sq * (1.f / DM) - mean * mean;
  float rstd = rsqrtf(var + 1e-5f);
  float4 gg = ((const float4*)g)[tid];
  float4 bb = ((const float4*)be)[tid];
  float xl[4];
  xl[0] = (v.x - mean) * rstd * gg.x + bb.x;
  xl[1] = (v.y - mean) * rstd * gg.y + bb.y;
  xl[2] = (v.z - mean) * rstd * gg.z + bb.z;
  xl[3] = (v.w - mean) * rstd * gg.w + bb.w;
  ushort4 u;
  u.x = f2bf(xl[0]); u.y = f2bf(xl[1]); u.z = f2bf(xl[2]); u.w = f2bf(xl[3]);
  ((ushort4*)(obf + (size_t)t * DM))[tid] = u;

  float pl[8], pn[8];
  #pragma unroll
  for (int e = 0; e < 8; e++) { pl[e] = 0.f; pn[e] = 0.f; }
  #pragma unroll
  for (int j = 0; j < 4; j++) {
    int d = tid * 4 + j;
    float xv = xl[j];
    const float4* wr = (const float4*)(Wr + (size_t)d * 8);
    const float4* wn = (const float4*)(Wn + (size_t)d * 8);
    float4 a0 = wr[0], a1 = wr[1], c0 = wn[0], c1 = wn[1];
    pl[0] += xv * a0.x; pl[1] += xv * a0.y; pl[2] += xv * a0.z; pl[3] += xv * a0.w;
    pl[4] += xv * a1.x; pl[5] += xv * a1.y; pl[6] += xv * a1.z; pl[7] += xv * a1.w;
    pn[0] += xv * c0.x; pn[1] += xv * c0.y; pn[2] += xv * c0.z; pn[3] += xv * c0.w;
    pn[4] += xv * c1.x; pn[5] += xv * c1.y; pn[6] += xv * c1.z; pn[7] += xv * c1.w;
  }
  for (int o = 32; o; o >>= 1) {
    #pragma unroll
    for (int e = 0; e < 8; e++) { pl[e] += __shfl_down(pl[e], o); pn[e] += __shfl_down(pn[e], o); }
  }
  __shared__ float sl[4][8], sn[4][8];
  if ((tid & 63) == 0) {
    int w = tid >> 6;
    #pragma unroll
    for (int e = 0; e < 8; e++) { sl[w][e] = pl[e]; sn[w][e] = pn[e]; }
  }
  __syncthreads();
  if (tid == 0) {
    float noisy[8];
    #pragma unroll
    for (int e = 0; e < 8; e++) {
      float l  = sl[0][e] + sl[1][e] + sl[2][e] + sl[3][e] + br[e];
      float nn = sn[0][e] + sn[1][e] + sn[2][e] + sn[3][e] + bn[e];
      float sp = (nn > 20.f) ? nn : log1pf(expf(nn));
      noisy[e] = l + noise[(size_t)t * 8 + e] * sp;
    }
    int i0 = 0;
    for (int e = 1; e < 8; e++) if (noisy[e] > noisy[i0]) i0 = e;
    int i1 = (i0 == 0) ? 1 : 0;
    for (int e = 0; e < 8; e++) if (e != i0 && noisy[e] > noisy[i1]) i1 = e;
    float e1 = expf(noisy[i1] - noisy[i0]);
    float zz = 1.f + e1;
    gates[t * 2] = 1.f / zz; gates[t * 2 + 1] = e1 / zz;
    topidx[t * 2] = i0; topidx[t * 2 + 1] = i1;
  }
}

// ---------------- layernorm -> hi/lo bf16 pair (attention path) ----------------
__global__ void k_ln2(const float* __restrict__ in, const float* __restrict__ g,
                      const float* __restrict__ be, u16* __restrict__ oh,
                      u16* __restrict__ ol) {
  int t = blockIdx.x, tid = threadIdx.x;
  float4 v = ((const float4*)(in + (size_t)t * DM))[tid];
  float s = v.x + v.y + v.z + v.w;
  float sq = v.x*v.x + v.y*v.y + v.z*v.z + v.w*v.w;
  for (int o = 32; o; o >>= 1) { s += __shfl_down(s, o); sq += __shfl_down(sq, o); }
  __shared__ float ss[4], sqs[4];
  if ((tid & 63) == 0) { ss[tid >> 6] = s; sqs[tid >> 6] = sq; }
  __syncthreads();
  s  = ss[0] + ss[1] + ss[2] + ss[3];
  sq = sqs[0] + sqs[1] + sqs[2] + sqs[3];
  float mean = s * (1.f / DM);
  float var  = sq * (1.f / DM) - mean * mean;
  float rstd = rsqrtf(var + 1e-5f);
  float4 gg = ((const float4*)g)[tid];
  float4 bb = ((const float4*)be)[tid];
  float o4[4];
  o4[0] = (v.x - mean) * rstd * gg.x + bb.x;
  o4[1] = (v.y - mean) * rstd * gg.y + bb.y;
  o4[2] = (v.z - mean) * rstd * gg.z + bb.z;
  o4[3] = (v.w - mean) * rstd * gg.w + bb.w;
  ushort4 uh, ul;
  u16* ph = (u16*)&uh; u16* pl = (u16*)&ul;
  #pragma unroll
  for (int i = 0; i < 4; i++) {
    u16 hi = f2bf(o4[i]); ph[i] = hi; pl[i] = f2bf(o4[i] - bf2f(hi));
  }
  ((ushort4*)(oh + (size_t)t * DM))[tid] = uh;
  ((ushort4*)(ol + (size_t)t * DM))[tid] = ul;
}

// ---------------- transpose f32 [K,N] -> hi/lo bf16 [N,K] (attention weights) ----------------
__global__ void k_tcvt_split(const float* __restrict__ src, u16* __restrict__ dh,
                             u16* __restrict__ dl, int K, int N) {
  __shared__ float t[32][33];
  int k0 = blockIdx.x * 32, n0 = blockIdx.y * 32;
  int tx = threadIdx.x, ty = threadIdx.y;
  #pragma unroll
  for (int i = 0; i < 4; i++) t[ty + 8*i][tx] = src[(size_t)(k0 + ty + 8*i) * N + n0 + tx];
  __syncthreads();
  int u = ty * 32 + tx;
  int r = u >> 3, kq = u & 7;
  ushort4 oh, ol;
  u16* ph = (u16*)&oh; u16* pl = (u16*)&ol;
  #pragma unroll
  for (int i = 0; i < 4; i++) {
    float v = t[kq*4+i][r];
    u16 hi = f2bf(v); ph[i] = hi; pl[i] = f2bf(v - bf2f(hi));
  }
  *(ushort4*)&dh[(size_t)(n0 + r) * K + k0 + kq*4] = oh;
  *(ushort4*)&dl[(size_t)(n0 + r) * K + k0 + kq*4] = ol;
}

// ---------------- transpose f32 [K,N] -> bf16 [N,K], 64x64 tiles, 16-expert dual-source ----------------
__global__ void k_tcvt64(const float* __restrict__ srcA, const float* __restrict__ srcB,
                         u16* __restrict__ dst, int K, int N) {
  __shared__ float t[64][65];
  int z = blockIdx.z;
  const float* src = (z < 8) ? srcA + (size_t)z * K * N : srcB + (size_t)(z - 8) * K * N;
  u16* d = dst + (size_t)z * K * N;
  int k0 = blockIdx.x * 64, n0 = blockIdx.y * 64;
  int u = threadIdx.y * 32 + threadIdx.x;
  #pragma unroll
  for (int i = 0; i < 4; i++) {
    int idx = u + i * 256;
    int kr = idx >> 4, nq = (idx & 15) * 4;
    float4 v = *(const float4*)&src[(size_t)(k0 + kr) * N + n0 + nq];
    t[kr][nq] = v.x; t[kr][nq+1] = v.y; t[kr][nq+2] = v.z; t[kr][nq+3] = v.w;
  }
  __syncthreads();
  #pragma unroll
  for (int j = 0; j < 2; j++) {
    int idx = u + j * 256;
    int nr = idx >> 3, kq = (idx & 7) * 8;
    ushort4 o0, o1;
    u16* p0 = (u16*)&o0; u16* p1 = (u16*)&o1;
    #pragma unroll
    for (int i = 0; i < 4; i++) p0[i] = f2bf(t[kq + i][nr]);
    #pragma unroll
    for (int i = 0; i < 4; i++) p1[i] = f2bf(t[kq + 4 + i][nr]);
    *(ushort4*)&d[(size_t)(n0 + nr) * K + k0 + kq]     = o0;
    *(ushort4*)&d[(size_t)(n0 + nr) * K + k0 + kq + 4] = o1;
  }
}

// ---------------- causal softmax f32 -> att hi/lo bf16 in place ----------------
__global__ void k_softmax_h(float* __restrict__ scores) {
  int q = blockIdx.x, bh = blockIdx.y, tid = threadIdx.x;
  float* row = scores + ((size_t)bh * 512 + q) * 512;
  u16* orow = (u16*)row;
  const float scale = 0.088388347648318447f; // 128^-0.5
  int j0 = tid * 2;
  float v0 = -1e30f, v1 = -1e30f;
  if (j0 <= q)     v0 = row[j0] * scale;
  if (j0 + 1 <= q) v1 = row[j0 + 1] * scale;
  float m = fmaxf(v0, v1);
  for (int o = 32; o; o >>= 1) m = fmaxf(m, __shfl_down(m, o));
  __shared__ float sm[4], ssum[4];
  if ((tid & 63) == 0) sm[tid >> 6] = m;
  __syncthreads();
  m = fmaxf(fmaxf(sm[0], sm[1]), fmaxf(sm[2], sm[3]));
  float p0 = (j0 <= q)     ? expf(v0 - m) : 0.f;
  float p1 = (j0 + 1 <= q) ? expf(v1 - m) : 0.f;
  float s = p0 + p1;
  for (int o = 32; o; o >>= 1) s += __shfl_down(s, o);
  if ((tid & 63) == 0) ssum[tid >> 6] = s;
  __syncthreads();
  s = ssum[0] + ssum[1] + ssum[2] + ssum[3];
  float inv = 1.f / s;
  float pi0 = p0 * inv, pi1 = p1 * inv;
  u16 h0 = f2bf(pi0), h1 = f2bf(pi1);
  orow[j0]       = h0; orow[j0 + 1]       = h1;
  orow[512 + j0] = f2bf(pi0 - bf2f(h0));
  orow[512 + j0 + 1] = f2bf(pi1 - bf2f(h1));
}

// ---------------- split-bf16 3-pass MFMA GEMM (attention path) ----------------
constexpr int HOP_QKV    = 0;
constexpr int HOP_SCORES = 1;
constexpr int HOP_PV     = 2;
constexpr int HOP_PROJ   = 3;

struct GemmHArgs {
  const u16 *Ah, *Al, *Bh, *Bl;
  u16 *D0h, *D0l, *D1h, *D1l, *D2h, *D2l;
  float *Cf;
  const float *bias, *resid, *pos;
  int lda, ldb, K;
};

template<int OP>
__launch_bounds__(256)
__global__ void gemm_h(GemmHArgs p) {
  int bx, by, z;
  if constexpr (OP == HOP_QKV) {
    int bid = blockIdx.x; int xcd = bid & 7, slot = bid >> 3;
    by = xcd * 3 + (slot >> 5); bx = slot & 31; z = 0;
  } else if constexpr (OP == HOP_PROJ) {
    int bid = blockIdx.x; by = bid & 7; bx = bid >> 3; z = 0;
  } else if constexpr (OP == HOP_SCORES) { // dense triangular: 10 tiles x 64 bh
    int bid = blockIdx.x; z = bid / 10; int t = bid % 10;
    bx = (t >= 6) ? 3 : (t >= 3) ? 2 : (t >= 1) ? 1 : 0;
    by = t - ((bx * (bx + 1)) >> 1);
  } else {
    bx = blockIdx.x; by = blockIdx.y; z = blockIdx.z;
  }

  const u16 *Ahb, *Alb, *Bhb, *Blb;
  if constexpr (OP == HOP_SCORES) {
    size_t off = (size_t)(z >> 3) * 524288 + (size_t)(z & 7) * 128;
    Ahb = p.Ah + off; Alb = p.Al + off; Bhb = p.Bh + off; Blb = p.Bl + off;
  } else if constexpr (OP == HOP_PV) {
    size_t aoff = (size_t)z * 524288;
    Ahb = p.Ah + aoff; Alb = p.Ah + aoff + 512;
    size_t boff = (size_t)z * 65536;
    Bhb = p.Bh + boff; Blb = p.Bl + boff;
  } else {
    Ahb = p.Ah; Alb = p.Al; Bhb = p.Bh; Blb = p.Bl;
  }

  int kmax = p.K;
  if constexpr (OP == HOP_PV) { int lim = bx * 128 + 128; kmax = lim < p.K ? lim : p.K; }
  int nt = kmax >> 5;

  __shared__ __align__(16) u16 As[2 * 4096];
  __shared__ __align__(16) u16 Bs[2 * 4096];

  int tid = threadIdx.x, lane = tid & 63, wid = tid >> 6;
  int srow = wid * 16 + (lane >> 2), skoff = (lane & 3) * 8;
  int lo0 = (wid * 16) * 32, lo1 = ((wid + 4) * 16) * 32;
  int wr = wid >> 1, wc = wid & 1, fm = lane & 15, fk = (lane >> 4) * 8;

  f32x4 acc[4][4] = {};
  const size_t lda = p.lda, ldb = p.ldb;

  #pragma unroll 1
  for (int pass = 0; pass < 3; ++pass) {
    const u16* Ab = (pass < 2) ? Ahb : Alb;
    const u16* Bb = (pass & 1) ? Blb : Bhb;
    const u16* aptr0 = Ab + (size_t)(bx * 128 + srow) * lda + skoff;
    const u16* aptr1 = Ab + (size_t)(bx * 128 + 64 + srow) * lda + skoff;
    const u16* bptr0 = Bb + (size_t)(by * 128 + srow) * ldb + skoff;
    const u16* bptr1 = Bb + (size_t)(by * 128 + 64 + srow) * ldb + skoff;

    gl_lds16(aptr0, &As[lo0]); gl_lds16(aptr1, &As[lo1]);
    gl_lds16(bptr0, &Bs[lo0]); gl_lds16(bptr1, &Bs[lo1]);
    __syncthreads();
    int cur = 0;
    for (int t = 0; t < nt; ++t) {
      if (t + 1 < nt) {
        int nxt = (cur ^ 1) * 4096;
        int k0 = (t + 1) * 32;
        gl_lds16(aptr0 + k0, &As[nxt + lo0]); gl_lds16(aptr1 + k0, &As[nxt + lo1]);
        gl_lds16(bptr0 + k0, &Bs[nxt + lo0]); gl_lds16(bptr1 + k0, &Bs[nxt + lo1]);
      }
      int cb = cur * 4096;
      bf16x8 af[4], bfr[4];
      #pragma unroll
      for (int i = 0; i < 4; ++i) {
        af[i]  = *(const bf16x8*)&As[cb + (wr * 64 + i * 16 + fm) * 32 + fk];
        bfr[i] = *(const bf16x8*)&Bs[cb + (wc * 64 + i * 16 + fm) * 32 + fk];
      }
      #pragma unroll
      for (int mi = 0; mi < 4; ++mi)
        #pragma unroll
        for (int ni = 0; ni < 4; ++ni)
          acc[mi][ni] = __builtin_amdgcn_mfma_f32_16x16x32_bf16(af[mi], bfr[ni], acc[mi][ni], 0, 0, 0);
      __syncthreads();
      cur ^= 1;
    }
  }

  int rb = (lane >> 4) * 4, cl = lane & 15;
  #pragma unroll
  for (int mi = 0; mi < 4; ++mi)
    #pragma unroll
    for (int ni = 0; ni < 4; ++ni)
      #pragma unroll
      for (int j = 0; j < 4; ++j) {
        int m = bx * 128 + wr * 64 + mi * 16 + rb + j;
        int n = by * 128 + wc * 64 + ni * 16 + cl;
        float v = acc[mi][ni][j];
        if constexpr (OP == HOP_QKV) {
          u16 hi = f2bf(v); u16 lo = f2bf(v - bf2f(hi));
          int sel = n >> 10, nn = n & 1023;
          if (sel == 0) {
            p.D0h[(size_t)m * DM + nn] = hi; p.D0l[(size_t)m * DM + nn] = lo;
          } else if (sel == 1) {
            p.D1h[(size_t)m * DM + nn] = hi; p.D1l[(size_t)m * DM + nn] = lo;
          } else {
            size_t idx = (size_t)((m >> 9) * 8 + (nn >> 7)) * 65536 + (size_t)(nn & 127) * 512 + (m & 511);
            p.D2h[idx] = hi; p.D2l[idx] = lo;
          }
        } else if constexpr (OP == HOP_SCORES) {
          p.Cf[(size_t)z * 262144 + (size_t)m * 512 + n] = v;
        } else if constexpr (OP == HOP_PV) {
          u16 hi = f2bf(v); u16 lo = f2bf(v - bf2f(hi));
          size_t idx = (size_t)(z >> 3) * 524288 + (size_t)m * 1024 + (size_t)(z & 7) * 128 + n;
          p.D0h[idx] = hi; p.D0l[idx] = lo;
        } else { // HOP_PROJ
          size_t idx = (size_t)m * 1024 + n;
          p.Cf[idx] = v + p.bias[n] + p.resid[idx] + p.pos[(size_t)(m & 511) * 1024 + n];
        }
      }
}

// ---------------- bf16 MFMA 128x128 TN GEMM, 2-phase dbuf, 16-expert merged (MoE) ----------------
constexpr int OP_MOE1 = 0; // gathered A rows (joblist -> xlnb[2*TOK]), bf16 C=relu(acc+b1)
constexpr int OP_MOE2 = 1; // contiguous padded A rows, f32 C=acc+b2

struct GemmArgs {
  const u16* A; const u16* B; void* C;
  const float* b1a; const float* b1b;   // per-half bias arrays (8 experts each)
  const int* joblist; const int* seg;   // seg[0..16]
  int lda, ldb, K;
};

template<int OP>
__launch_bounds__(256)
__global__ void gemm_k(GemmArgs p) {
  int bid = blockIdx.x;
  int xcd = bid & 7, slot = bid >> 3;
  int bx, by;
  if constexpr (OP == OP_MOE1) {
    // grid 4608 = 8 x 576: XCD c owns by in [4c,4c+4); bx 0..143
    by = xcd * 4 + (slot & 3);
    bx = slot >> 2;
  } else {
    // grid 1152 = 8 x 144: XCD c owns bx in [18c,18c+18); by 0..7
    bx = xcd * 18 + (slot >> 3);
    by = slot & 7;
  }
  int r0g = bx * 128;
  if (r0g >= p.seg[16]) return;
  int z = 0;
  #pragma unroll
  for (int e = 1; e < 16; ++e) z += (r0g >= p.seg[e]) ? 1 : 0;
  const u16* Bbase = p.B + (size_t)z * 4194304;
  const float* bias = (z < 8) ? p.b1a + (size_t)z * (OP == OP_MOE1 ? FF : DM)
                              : p.b1b + (size_t)(z - 8) * (OP == OP_MOE1 ? FF : DM);

  __shared__ __align__(16) u16 As[2 * 4096];
  __shared__ __align__(16) u16 Bs[2 * 4096];

  int tid = threadIdx.x;
  int lane = tid & 63, wid = tid >> 6;

  int srow = wid * 16 + (lane >> 2);
  int skoff = (lane & 3) * 8;

  const u16 *aptr0, *aptr1;
  if constexpr (OP == OP_MOE1) {
    int j0 = p.joblist[r0g + srow];
    int j1 = p.joblist[r0g + 64 + srow];
    aptr0 = p.A + (size_t)(j0 < 0 ? 0 : j0) * p.lda + skoff;
    aptr1 = p.A + (size_t)(j1 < 0 ? 0 : j1) * p.lda + skoff;
  } else {
    aptr0 = p.A + (size_t)(r0g + srow) * p.lda + skoff;
    aptr1 = p.A + (size_t)(r0g + 64 + srow) * p.lda + skoff;
  }
  const u16* bptr0 = Bbase + (size_t)(by * 128 + srow) * p.ldb + skoff;
  const u16* bptr1 = Bbase + (size_t)(by * 128 + 64 + srow) * p.ldb + skoff;

  int lo0 = (wid * 16) * 32;
  int lo1 = ((wid + 4) * 16) * 32;

  int wr = wid >> 1, wc = wid & 1;
  int fm = lane & 15;
  int fk = (lane >> 4) * 8;

  f32x4 acc[4][4] = {};
  int nt = p.K >> 5;

  gl_lds16(aptr0, &As[lo0]); gl_lds16(aptr1, &As[lo1]);
  gl_lds16(bptr0, &Bs[lo0]); gl_lds16(bptr1, &Bs[lo1]);
  __syncthreads();

  int cur = 0;
  for (int t = 0; t < nt; ++t) {
    if (t + 1 < nt) {
      int nxt = (cur ^ 1) * 4096;
      int k0 = (t + 1) * 32;
      gl_lds16(aptr0 + k0, &As[nxt + lo0]); gl_lds16(aptr1 + k0, &As[nxt + lo1]);
      gl_lds16(bptr0 + k0, &Bs[nxt + lo0]); gl_lds16(bptr1 + k0, &Bs[nxt + lo1]);
    }
    int cb = cur * 4096;
    bf16x8 af[4], bfr[4];
    #pragma unroll
    for (int i = 0; i < 4; ++i) {
      af[i]  = *(const bf16x8*)&As[cb + (wr * 64 + i * 16 + fm) * 32 + fk];
      bfr[i] = *(const bf16x8*)&Bs[cb + (wc * 64 + i * 16 + fm) * 32 + fk];
    }
    #pragma unroll
    for (int mi = 0; mi < 4; ++mi)
      #pragma unroll
      for (int ni = 0; ni < 4; ++ni)
        acc[mi][ni] = __builtin_amdgcn_mfma_f32_16x16x32_bf16(af[mi], bfr[ni], acc[mi][ni], 0, 0, 0);
    __syncthreads();
    cur ^= 1;
  }

  int rb = (lane >> 4) * 4;
  int cl = lane & 15;
  #pragma unroll
  for (int mi = 0; mi < 4; ++mi)
    #pragma unroll
    for (int ni = 0; ni < 4; ++ni)
      #pragma unroll
      for (int j = 0; j < 4; ++j) {
        int m = r0g + wr * 64 + mi * 16 + rb + j;
        int n = by * 128 + wc * 64 + ni * 16 + cl;
        float v = acc[mi][ni][j];
        if constexpr (OP == OP_MOE1) {
          float t2 = v + bias[n];
          t2 = t2 > 0.f ? t2 : 0.f;
          ((u16*)p.C)[(size_t)m * FF + n] = f2bf(t2);
        } else {
          ((float*)p.C)[(size_t)m * DM + n] = v + bias[n];
        }
      }
}

// ---------------- MoE bookkeeping (16-expert merged) ----------------
__global__ void k_moe_init(int* cnt, int* cnt2, int* joblist) {
  int i = blockIdx.x * 256 + threadIdx.x;
  if (i < JOBCAP) joblist[i] = -1;
  if (i < 16) { cnt[i] = 0; cnt2[i] = 0; }
}
__global__ void k_moe_count(const int* __restrict__ topidx, int* __restrict__ cnt) {
  int t = blockIdx.x * 256 + threadIdx.x;     // global token 0..2*TOK
  if (t >= 2 * TOK) return;
  int lo = (t >= TOK) ? 8 : 0;
  atomicAdd(&cnt[topidx[t * 2] + lo], 1);
  atomicAdd(&cnt[topidx[t * 2 + 1] + lo], 1);
}
__global__ void k_moe_offsets(const int* __restrict__ cnt, int* __restrict__ seg) {
  if (threadIdx.x == 0) {
    int o = 0;
    for (int e = 0; e < 16; e++) { seg[e] = o; o += (cnt[e] + 127) & ~127; }
    seg[16] = o;
  }
}
__global__ void k_moe_scatter(const int* __restrict__ topidx, int* __restrict__ cnt2,
                              const int* __restrict__ seg, int* __restrict__ joblist,
                              int* __restrict__ tokpos) {
  int t = blockIdx.x * 256 + threadIdx.x;
  if (t >= 2 * TOK) return;
  int lo = (t >= TOK) ? 8 : 0;
  #pragma unroll
  for (int s = 0; s < 2; s++) {
    int e = topidx[t * 2 + s] + lo;
    int p = atomicAdd(&cnt2[e], 1);
    int pos = seg[e] + p;
    joblist[pos] = t;                 // global row into xlnb[2*TOK]
    tokpos[t * 2 + s] = pos;
  }
}
__global__ void k_combine(const float* __restrict__ y, const float* __restrict__ gates,
                          const int* __restrict__ tokpos, float* __restrict__ out) {
  int t = blockIdx.x, tid = threadIdx.x;
  int p0 = tokpos[t * 2], p1 = tokpos[t * 2 + 1];
  float g0 = gates[t * 2], g1 = gates[t * 2 + 1];
  float4 a = ((const float4*)(y + (size_t)p0 * DM))[tid];
  float4 b = ((const float4*)(y + (size_t)p1 * DM))[tid];
  float4 o;
  o.x = g0 * a.x + g1 * b.x; o.y = g0 * a.y + g1 * b.y;
  o.z = g0 * a.z + g1 * b.z; o.w = g0 * a.w + g1 * b.w;
  ((float4*)(out + (size_t)t * DM))[tid] = o;
}

// ---------------- feature mean (two-stage) + classifier ----------------
__global__ void k_feat1(const float* __restrict__ second, float* __restrict__ part) {
  int b = blockIdx.x, c = blockIdx.y, tid = threadIdx.x;
  const float* p = second + ((size_t)b * SEQ + (size_t)c * 64) * DM;
  float4 s = {0.f, 0.f, 0.f, 0.f};
  for (int j = 0; j < 64; ++j) {
    float4 v = ((const float4*)(p + (size_t)j * DM))[tid];
    s.x += v.x; s.y += v.y; s.z += v.z; s.w += v.w;
  }
  ((float4*)(part + (size_t)(b * 8 + c) * DM))[tid] = s;
}
__global__ void k_feat2(const float* __restrict__ part, float* __restrict__ feat) {
  int i = blockIdx.x * 256 + threadIdx.x;
  int b = i >> 10, d = i & 1023;
  float s = 0.f;
  #pragma unroll
  for (int c = 0; c < 8; ++c) s += part[(size_t)(b * 8 + c) * DM + d];
  feat[i] = s * (1.f / SEQ);
}
__global__ void k_cls(const float* __restrict__ feat, const float* __restrict__ Wc,
                      const float* __restrict__ bc, float* __restrict__ cls) {
  int o = blockIdx.x; int b = o / 10, n = o % 10; int l = threadIdx.x;
  float s = 0.f;
  for (int d = l; d < DM; d += 64) s += feat[b * DM + d] * Wc[(size_t)d * 10 + n];
  for (int off = 32; off; off >>= 1) s += __shfl_down(s, off);
  if (l == 0) cls[o] = s + bc[n];
}

// ---------------- launch ----------------
extern "C" void kernel_launch(void* const* d_in, const int* in_sizes, int n_in,
                              void* d_out, int out_size, void* d_ws, size_t ws_size,
                              hipStream_t stream) {
  const int*   ids    = (const int*)d_in[0];
  const float* emb    = (const float*)d_in[2];
  const float* pos    = (const float*)d_in[3];
  const float* Wq     = (const float*)d_in[4];
  const float* Wk     = (const float*)d_in[5];
  const float* Wv     = (const float*)d_in[6];
  const float* Wo     = (const float*)d_in[7];
  const float* bo     = (const float*)d_in[8];
  const float* g1     = (const float*)d_in[9];
  const float* be1    = (const float*)d_in[10];
  const float* g2     = (const float*)d_in[11];
  const float* be2    = (const float*)d_in[12];
  const float* g3     = (const float*)d_in[13];
  const float* be3    = (const float*)d_in[14];
  const float* Wr1    = (const float*)d_in[15];
  const float* br1    = (const float*)d_in[16];
  const float* Wn1    = (const float*)d_in[17];
  const float* bn1    = (const float*)d_in[18];
  const float* W1a    = (const float*)d_in[19];
  const float* b1a    = (const float*)d_in[20];
  const float* W2a    = (const float*)d_in[21];
  const float* b2a    = (const float*)d_in[22];
  const float* Wr2    = (const float*)d_in[23];
  const float* br2    = (const float*)d_in[24];
  const float* Wn2    = (const float*)d_in[25];
  const float* bn2    = (const float*)d_in[26];
  const float* W1b    = (const float*)d_in[27];
  const float* b1b    = (const float*)d_in[28];
  const float* W2b    = (const float*)d_in[29];
  const float* b2b    = (const float*)d_in[30];
  const float* noise1 = (const float*)d_in[31];
  const float* noise2 = (const float*)d_in[32];
  const float* Wc     = (const float*)d_in[33];
  const float* bc     = (const float*)d_in[34];

  char* wsp = (char*)d_ws; size_t off = 0;
  auto alloc = [&](size_t bytes) -> void* {
    void* p = wsp + off; off += (bytes + 255) & ~(size_t)255; return p;
  };
  char*  G     = (char*)alloc(360710144);              // phase-overlaid big region (344MB)
  float* x     = (float*)alloc((size_t)TOK * DM * 4);
  float* x2    = (float*)alloc((size_t)TOK * DM * 4);
  u16*   xlnb  = (u16*)alloc((size_t)2 * TOK * DM * 2);   // both layers' LN
  float* gates  = (float*)alloc(2 * TOK * 2 * 4);
  int*   topidx = (int*)alloc(2 * TOK * 2 * 4);
  int*   cnt    = (int*)alloc(16 * 4);
  int*   cnt2   = (int*)alloc(16 * 4);
  int*   seg    = (int*)alloc(24 * 4);
  int*   joblist= (int*)alloc(JOBCAP * 4);
  int*   tokpos = (int*)alloc(2 * TOK * 2 * 4);
  float* fpart  = (float*)alloc(64 * DM * 4);
  (void)ws_size; (void)in_sizes; (void)n_in; (void)out_size;

  // attention-phase views (~164MB of G)
  u16* WQKVTh = (u16*)(G + 0);
  u16* WQKVTl = (u16*)(G + 6291456);
  u16* WOTh   = (u16*)(G + 12582912);
  u16* WOTl   = (u16*)(G + 14680064);
  u16* XLNH   = (u16*)(G + 16777216);
  u16* XLNL   = (u16*)(G + 25165824);
  u16* QH     = (u16*)(G + 33554432);
  u16* QL     = (u16*)(G + 41943040);
  u16* KH     = (u16*)(G + 50331648);
  u16* KL     = (u16*)(G + 58720256);
  u16* VTh    = (u16*)(G + 67108864);
  u16* VTl    = (u16*)(G + 75497472);
  u16* OH     = (u16*)(G + 83886080);
  u16* OL     = (u16*)(G + 92274688);
  float* SC   = (float*)(G + 100663296);  // [64][512][512] f32 -> att hi/lo in place
  // moe-phase views (344MB of G; attention buffers dead by then)
  u16*   H    = (u16*)(G + 0);            // [18432][4096] bf16 (151MB)
  float* Y    = (float*)(G + 150994944);  // [18432][1024] f32 (75.5MB)
  u16*   WBUF = (u16*)(G + 226492416);    // 16 experts' weights bf16 (128MB)

  float* out_first  = (float*)d_out;
  float* out_second = out_first + (size_t)TOK * DM;
  float* feat       = out_first + (size_t)2 * TOK * DM;
  float* cls        = feat + 8 * DM;

  dim3 tb(32, 8);
  // ---- attention phase: split-bf16 3-pass ----
  hipLaunchKernelGGL(k_tcvt_split, dim3(32, 32), tb, 0, stream, Wq, WQKVTh,            WQKVTl,            DM, DM);
  hipLaunchKernelGGL(k_tcvt_split, dim3(32, 32), tb, 0, stream, Wk, WQKVTh + 1048576,  WQKVTl + 1048576,  DM, DM);
  hipLaunchKernelGGL(k_tcvt_split, dim3(32, 32), tb, 0, stream, Wv, WQKVTh + 2097152,  WQKVTl + 2097152,  DM, DM);
  hipLaunchKernelGGL(k_tcvt_split, dim3(32, 32), tb, 0, stream, Wo, WOTh,              WOTl,              DM, DM);
  hipLaunchKernelGGL(k_embed, dim3(TOK), dim3(256), 0, stream, ids, emb, x);
  hipLaunchKernelGGL(k_ln2, dim3(TOK), dim3(256), 0, stream, x, g1, be1, XLNH, XLNL);

  GemmHArgs qa{};
  qa.Ah = XLNH; qa.Al = XLNL; qa.Bh = WQKVTh; qa.Bl = WQKVTl;
  qa.D0h = QH; qa.D0l = QL; qa.D1h = KH; qa.D1l = KL; qa.D2h = VTh; qa.D2l = VTl;
  qa.lda = DM; qa.ldb = DM; qa.K = DM;
  hipLaunchKernelGGL(gemm_h<HOP_QKV>, dim3(768), dim3(256), 0, stream, qa);

  GemmHArgs sa{};
  sa.Ah = QH; sa.Al = QL; sa.Bh = KH; sa.Bl = KL; sa.Cf = SC;
  sa.lda = DM; sa.ldb = DM; sa.K = HD;
  hipLaunchKernelGGL(gemm_h<HOP_SCORES>, dim3(640), dim3(256), 0, stream, sa);
  hipLaunchKernelGGL(k_softmax_h, dim3(SEQ, 64), dim3(256), 0, stream, SC);

  GemmHArgs pa{};
  pa.Ah = (const u16*)SC; pa.Bh = VTh; pa.Bl = VTl;
  pa.D0h = OH; pa.D0l = OL;
  pa.lda = 1024; pa.ldb = 512; pa.K = SEQ;
  hipLaunchKernelGGL(gemm_h<HOP_PV>, dim3(4, 1, 64), dim3(256), 0, stream, pa);

  GemmHArgs pj{};
  pj.Ah = OH; pj.Al = OL; pj.Bh = WOTh; pj.Bl = WOTl; pj.Cf = x2;
  pj.bias = bo; pj.resid = x; pj.pos = pos;
  pj.lda = DM; pj.ldb = DM; pj.K = DM;
  hipLaunchKernelGGL(gemm_h<HOP_PROJ>, dim3(256), dim3(256), 0, stream, pj);

  // ---- MoE phase: both layers merged into one 16-expert batch ----
  hipLaunchKernelGGL(k_lnrouter, dim3(TOK), dim3(256), 0, stream, x2, g2, be2,
                     Wr1, br1, Wn1, bn1, noise1, xlnb, gates, topidx);
  hipLaunchKernelGGL(k_lnrouter, dim3(TOK), dim3(256), 0, stream, x2, g3, be3,
                     Wr2, br2, Wn2, bn2, noise2, xlnb + (size_t)TOK * DM,
                     gates + (size_t)TOK * 2, topidx + (size_t)TOK * 2);
  hipLaunchKernelGGL(k_moe_init, dim3(72), dim3(256), 0, stream, cnt, cnt2, joblist);
  hipLaunchKernelGGL(k_moe_count, dim3(32), dim3(256), 0, stream, topidx, cnt);
  hipLaunchKernelGGL(k_moe_offsets, dim3(1), dim3(64), 0, stream, cnt, seg);
  hipLaunchKernelGGL(k_moe_scatter, dim3(32), dim3(256), 0, stream, topidx, cnt2, seg, joblist, tokpos);

  hipLaunchKernelGGL(k_tcvt64, dim3(16, 64, 16), tb, 0, stream, W1a, W1b, WBUF, DM, FF);
  GemmArgs m1{};
  m1.A = xlnb; m1.B = WBUF; m1.C = H; m1.b1a = b1a; m1.b1b = b1b;
  m1.joblist = joblist; m1.seg = seg;
  m1.lda = DM; m1.ldb = DM; m1.K = DM;
  hipLaunchKernelGGL(gemm_k<OP_MOE1>, dim3(4608), dim3(256), 0, stream, m1);

  hipLaunchKernelGGL(k_tcvt64, dim3(64, 16, 16), tb, 0, stream, W2a, W2b, WBUF, FF, DM);
  GemmArgs m2{};
  m2.A = H; m2.B = WBUF; m2.C = Y; m2.b1a = b2a; m2.b1b = b2b;
  m2.joblist = joblist; m2.seg = seg;
  m2.lda = FF; m2.ldb = FF; m2.K = FF;
  hipLaunchKernelGGL(gemm_k<OP_MOE2>, dim3(1152), dim3(256), 0, stream, m2);

  hipLaunchKernelGGL(k_combine, dim3(TOK), dim3(256), 0, stream, Y, gates, tokpos, out_first);
  hipLaunchKernelGGL(k_combine, dim3(TOK), dim3(256), 0, stream, Y,
                     gates + (size_t)TOK * 2, tokpos + (size_t)TOK * 2, out_second);

  hipLaunchKernelGGL(k_feat1, dim3(8, 8), dim3(256), 0, stream, out_second, fpart);
  hipLaunchKernelGGL(k_feat2, dim3(32), dim3(256), 0, stream, fpart, feat);
  hipLaunchKernelGGL(k_cls, dim3(80), dim3(64), 0, stream, feat, Wc, bc, cls);
}